// Round 5
// baseline (1724.763 us; speedup 1.0000x reference)
//
#include <hip/hip_runtime.h>
#include <hip/hip_bf16.h>

// BiLSTM-CRF forward, MI355X gfx950.
// B=256, S=512, E=256, H=256, G=4H=1024, T=32, PAD=49999.
//
// Round-12 (= round-11 structure + three issue-reductions):
//   - lstm gates: fused-rcp forms, 5 exp2 + 3 rcp per element (was 5+5), clamped.
//   - hbuf 32B-block XOR swizzle (blk ^= col&7) on write+read: ds_read_b64
//     bank aliasing ~4-8way -> ~2way.
//   - crf: 2 sentences per wave (half-split), no cross-half shfl in scan chain.
//   Persistent pipeline unchanged: 32 lstm blocks (16 owned sentences each),
//   224 gemm workers, fine-grained span flags, parity-double-buffered gx.

typedef __bf16 bf16x8 __attribute__((ext_vector_type(8)));
typedef float f32x4 __attribute__((ext_vector_type(4)));
typedef unsigned int uint4v __attribute__((ext_vector_type(4)));

__device__ __forceinline__ unsigned short f2bf(float f) {
  union { float f; unsigned int u; } v; v.f = f;
  unsigned int r = v.u + 0x7fffu + ((v.u >> 16) & 1u);   // RNE
  return (unsigned short)(r >> 16);
}
__device__ __forceinline__ float bf2f(unsigned int lo16) {
  union { unsigned int u; float f; } v; v.u = lo16 << 16;
  return v.f;
}

__device__ __forceinline__ void wait_ge(int* p, int target) {
  if (threadIdx.x == 0) {
    while (__hip_atomic_load(p, __ATOMIC_RELAXED, __HIP_MEMORY_SCOPE_AGENT) < target)
      __builtin_amdgcn_s_sleep(2);
    (void)__hip_atomic_load(p, __ATOMIC_ACQUIRE, __HIP_MEMORY_SCOPE_AGENT);
  }
  __syncthreads();
}

// LDS-only barrier: no vmcnt(0) drain (keeps emission stores / gx prefetch
// loads in flight across the per-step h exchange).
__device__ __forceinline__ void lds_barrier() {
  asm volatile("s_waitcnt lgkmcnt(0)\n\ts_barrier" ::: "memory");
}

// ---------------- K0: weight conversion + flag reset ----------------
__global__ void cvt_weights(const float* __restrict__ wih_f, const float* __restrict__ wih_b,
                            const float* __restrict__ whh_f, const float* __restrict__ whh_b,
                            const float* __restrict__ wo,
                            unsigned short* __restrict__ wih,    // bf16 [2][1024][256]
                            unsigned char* __restrict__ whh8,    // fp8  [2][1024][256]
                            unsigned char* __restrict__ wout8,   // fp8  [32][512]
                            int* __restrict__ flags) {           // ready[512] + done[16]
  if (blockIdx.x == 0) {
    for (int f = threadIdx.x; f < 544; f += 256) flags[f] = 0;
  }
  int t = blockIdx.x * 256 + threadIdx.x;
  int i = t * 4;
  if (i < 524288) {
    const float* src = (i < 262144) ? wih_f : wih_b;
    f32x4 v = *(const f32x4*)(src + (i & 262143));
    uint2 p;
    p.x = f2bf(v[0]) | ((unsigned int)f2bf(v[1]) << 16);
    p.y = f2bf(v[2]) | ((unsigned int)f2bf(v[3]) << 16);
    *(uint2*)(wih + i) = p;
  } else if (i < 1048576) {
    int k = i - 524288;
    const float* src = (k < 262144) ? whh_f : whh_b;
    f32x4 v = *(const f32x4*)(src + (k & 262143));
    int r = 0;
    r = __builtin_amdgcn_cvt_pk_fp8_f32(v[0], v[1], r, false);
    r = __builtin_amdgcn_cvt_pk_fp8_f32(v[2], v[3], r, true);
    *(unsigned int*)(whh8 + k) = (unsigned int)r;
  } else if (i < 1064960) {
    int k = i - 1048576;
    f32x4 v = *(const f32x4*)(wo + k);
    int r = 0;
    r = __builtin_amdgcn_cvt_pk_fp8_f32(v[0], v[1], r, false);
    r = __builtin_amdgcn_cvt_pk_fp8_f32(v[2], v[3], r, true);
    *(unsigned int*)(wout8 + k) = (unsigned int)r;
  }
}

// ---------------- persistent roles ----------------
// gx layout: [parity][dir][32 s][256 b][1024 g] bf16
//   parity stride 16,777,216 elems; dir 8,388,608; s 262,144.
// flags: ready[k*32 + ss*8 + dir*4 + bt] (target 8 = nc tiles), done[512 + k]
//   (target 32 = lstm blocks).

__device__ void gemm_role(
    const float* __restrict__ emb, const int* __restrict__ sent, const int* __restrict__ lens,
    const unsigned short* __restrict__ wih,
    const float* __restrict__ bih_f, const float* __restrict__ bhh_f,
    const float* __restrict__ bih_b, const float* __restrict__ bhh_b,
    unsigned short* __restrict__ gx, int* flags,
    unsigned short* wtile, float* btile)
{
  int gb = blockIdx.x - 32;   // 0..223
  int tid = threadIdx.x, w = tid >> 6, lane = tid & 63, col = lane & 15, q = lane >> 4;
  int ns = w >> 2, cg = w & 3;
  int prev_chunk = -1;

  for (int idx = gb; idx < 4096; idx += 224) {
    int k = idx >> 8, t = idx & 255;
    // ss-major within chunk: early s-spans produced first
    int ss = t >> 6, rest = t & 63;
    int dir = (rest >> 5) & 1, nc = (rest >> 2) & 7, bt = rest & 3;
    if (k != prev_chunk) {
      prev_chunk = k;
      if (k >= 2) wait_ge(&flags[512 + k - 2], 32);   // parity reuse backpressure
    }
    int n0 = nc * 128, bbase = bt * 64;
    int sbase = k * 32 + ss * 8;

    if (sbase < lens[bbase]) {   // sorted desc: lens[bbase] = tile max
      const unsigned short* wsrc = wih + (size_t)dir * 262144;
#pragma unroll
      for (int it = 0; it < 8; it++) {
        int seg = it * 512 + tid;
        int row = seg >> 5, kc = (seg & 31) * 8;
        *(uint4v*)(wtile + row * 264 + kc) = *(const uint4v*)(wsrc + (size_t)(n0 + row) * 256 + kc);
      }
      const float* bi = dir ? bih_b : bih_f;
      const float* bh = dir ? bhh_b : bhh_f;
      if (tid < 128) btile[tid] = bi[n0 + tid] + bh[n0 + tid];
      __syncthreads();

      bf16x8 wf[8][4];
#pragma unroll
      for (int kt = 0; kt < 8; kt++)
#pragma unroll
        for (int nt = 0; nt < 4; nt++)
          wf[kt][nt] = *(const bf16x8*)(wtile + (ns * 64 + nt * 16 + col) * 264 + kt * 32 + q * 8);
      f32x4 bias[4];
#pragma unroll
      for (int nt = 0; nt < 4; nt++)
#pragma unroll
        for (int rr = 0; rr < 4; rr++)
          bias[nt][rr] = btile[ns * 64 + nt * 16 + q * 4 + rr];

      int bidx = bbase + cg * 16 + col;
      int len = lens[bidx];
      const int* srow = sent + bidx * 512;

      for (int i = 0; i < 8; i++) {
        int s = sbase + i;
        int s_eff = dir ? ((s < len) ? (len - 1 - s) : s) : s;
        int token = srow[s_eff];
        const float* ep = emb + (size_t)token * 256;
        bf16x8 xf[8];
#pragma unroll
        for (int kt = 0; kt < 8; kt++) {
          f32x4 a0 = *(const f32x4*)(ep + kt * 32 + q * 8);
          f32x4 a1 = *(const f32x4*)(ep + kt * 32 + q * 8 + 4);
          uint4v pk;
          pk[0] = f2bf(a0[0]) | ((unsigned int)f2bf(a0[1]) << 16);
          pk[1] = f2bf(a0[2]) | ((unsigned int)f2bf(a0[3]) << 16);
          pk[2] = f2bf(a1[0]) | ((unsigned int)f2bf(a1[1]) << 16);
          pk[3] = f2bf(a1[2]) | ((unsigned int)f2bf(a1[3]) << 16);
          xf[kt] = __builtin_bit_cast(bf16x8, pk);
        }
        f32x4 acc[4];
#pragma unroll
        for (int nt = 0; nt < 4; nt++) acc[nt] = bias[nt];
#pragma unroll
        for (int kt = 0; kt < 8; kt++)
#pragma unroll
          for (int nt = 0; nt < 4; nt++)
            acc[nt] = __builtin_amdgcn_mfma_f32_16x16x32_bf16(wf[kt][nt], xf[kt], acc[nt], 0, 0, 0);
        size_t off = (size_t)(k & 1) * 16777216 + (size_t)dir * 8388608
                   + (size_t)(s - k * 32) * 262144 + (size_t)bidx * 1024 + n0 + ns * 64;
#pragma unroll
        for (int nt = 0; nt < 4; nt++) {
          uint2 pk;
          pk.x = f2bf(acc[nt][0]) | ((unsigned int)f2bf(acc[nt][1]) << 16);
          pk.y = f2bf(acc[nt][2]) | ((unsigned int)f2bf(acc[nt][3]) << 16);
          *(uint2*)(gx + off + nt * 16 + q * 4) = pk;
        }
      }
    }
    // tile done: barrier drains this block's gx stores, then device-scope release
    __syncthreads();
    if (tid == 0)
      __hip_atomic_fetch_add(&flags[k * 32 + ss * 8 + dir * 4 + bt], 1,
                             __ATOMIC_RELEASE, __HIP_MEMORY_SCOPE_AGENT);
  }
}

__device__ void lstm_role(
    const unsigned short* __restrict__ gx,
    const unsigned char* __restrict__ whh8,
    const unsigned char* __restrict__ wout8,
    const float* __restrict__ bout,
    const int* __restrict__ lens,
    unsigned short* __restrict__ emit_f, unsigned short* __restrict__ emit_b,
    int* flags, unsigned char (*hb4)[16 * 264])
{
  int bx = blockIdx.x;                 // 0..31
  int dir = bx & 1, grp = bx >> 1, b0 = grp * 16;
  int bt = grp >> 2;                   // gemm sentence-tile group (64 sentences)
  int tid = threadIdx.x, w = tid >> 6, lane = tid & 63, col = lane & 15, q = lane >> 4;
  int maxlen = lens[b0];               // sorted desc
  int bcl = b0 + col;                  // owned sentence (all 16 cols real)
  int mylen = lens[bcl];
  int c7 = col & 7;                    // hbuf 32B-block swizzle key

  // ---- W_hh fp8 fragments fully into registers/AGPRs (64 x 8B), once ----
  const unsigned char* whb = whh8 + (size_t)dir * 262144;
  long wh[8][8];
#pragma unroll
  for (int kt = 0; kt < 8; kt++)
#pragma unroll
    for (int t = 0; t < 8; t++) {
      int row0 = (t & 3) * 256 + w * 32 + (t >> 2) * 16;
      wh[kt][t] = *(const long*)(whb + (size_t)(row0 + col) * 256 + kt * 32 + q * 8);
    }

  // ---- emission weights fp8: every wave holds tag-half (w&1)*16 ----
  long wo8[8];
  f32x4 bo4 = (f32x4){0.f, 0.f, 0.f, 0.f};
#pragma unroll
  for (int kt = 0; kt < 8; kt++)
    wo8[kt] = *(const long*)(wout8 + (size_t)((w & 1) * 16 + col) * 512 + dir * 256 + kt * 32 + q * 8);
  if (dir == 0) {
#pragma unroll
    for (int r = 0; r < 4; r++) bo4[r] = bout[(w & 1) * 16 + q * 4 + r];
  }
  unsigned short* ebase = dir ? emit_b : emit_f;

  // ---- persistent state (registers, whole sequence) ----
  float c8[8];
  long hf8[8];
#pragma unroll
  for (int i = 0; i < 8; i++) { c8[i] = 0.f; hf8[i] = 0; }

  const float NK  = -1.4426950408889634f;   // -log2(e)
  const float N2K = -2.8853900817779268f;   // -2*log2(e)

  for (int c = 0; c < 16; c++) {
    int s0 = c * 32;
    if (s0 < maxlen) {
      int cend = s0 + 32; if (cend > maxlen) cend = maxlen;
      const unsigned short* gbase = gx + (size_t)(c & 1) * 16777216 + (size_t)dir * 8388608
                                       + (size_t)bcl * 1024 + q * 4;
      for (int ss = 0; ss < 4; ss++) {
        int sp0 = s0 + ss * 8;
        if (sp0 >= maxlen) break;
        int spe = sp0 + 8; if (spe > cend) spe = cend;
        wait_ge(&flags[c * 32 + ss * 8 + dir * 4 + bt], 8);   // span produced

        uint2 gxr[8];
        {
          const unsigned short* gf = gbase + (size_t)(sp0 - s0) * 262144;
#pragma unroll
          for (int t = 0; t < 8; t++) {
            int row0 = (t & 3) * 256 + w * 32 + (t >> 2) * 16;
            gxr[t] = *(const uint2*)(gf + row0);
          }
        }

        for (int s = sp0; s < spe; s++) {
          f32x4 acc[8];
#pragma unroll
          for (int t = 0; t < 8; t++) {
            f32x4 a;
            a[0] = bf2f(gxr[t].x & 0xffffu); a[1] = bf2f(gxr[t].x >> 16);
            a[2] = bf2f(gxr[t].y & 0xffffu); a[3] = bf2f(gxr[t].y >> 16);
            acc[t] = a;
          }
          // prefetch gx for s+1 (within span only; span boundary reloads fresh)
          if (s + 1 < spe) {
            const unsigned short* gn = gbase + (size_t)(s + 1 - s0) * 262144;
#pragma unroll
            for (int t = 0; t < 8; t++) {
              int row0 = (t & 3) * 256 + w * 32 + (t >> 2) * 16;
              gxr[t] = *(const uint2*)(gn + row0);
            }
          }
          // h-part: fp8 MFMA, W resident
#pragma unroll
          for (int kt = 0; kt < 8; kt++) {
            long hv8 = hf8[kt];
#pragma unroll
            for (int t = 0; t < 8; t++)
              acc[t] = __builtin_amdgcn_mfma_f32_16x16x32_fp8_fp8(wh[kt][t], hv8, acc[t], 0, 0, 0);
          }
          // gates: 5 exp2 + 3 rcp per element (fused-rcp sigmoid*tanh forms)
          float hv[8];
#pragma unroll
          for (int a = 0; a < 2; a++)
#pragma unroll
            for (int r = 0; r < 4; r++) {
              float ig = acc[a * 4 + 0][r], fg = acc[a * 4 + 1][r];
              float gg = acc[a * 4 + 2][r], og = acc[a * 4 + 3][r];
              float ui = __builtin_amdgcn_exp2f(NK * ig);
              float uf = __builtin_amdgcn_exp2f(NK * fg);
              float uo = __builtin_amdgcn_exp2f(NK * og);
              float tg = __builtin_amdgcn_exp2f(fminf(N2K * gg, 80.0f));
              float cf = c8[a * 4 + r] * __builtin_amdgcn_rcpf(1.0f + uf);
              float cn = cf + (1.0f - tg) * __builtin_amdgcn_rcpf((1.0f + ui) * (1.0f + tg));
              c8[a * 4 + r] = cn;
              float tc = __builtin_amdgcn_exp2f(fminf(N2K * cn, 80.0f));
              hv[a * 4 + r] = (1.0f - tc) * __builtin_amdgcn_rcpf((1.0f + uo) * (1.0f + tc));
            }
          // write fp8 h to 8-deep LDS history (32B-block swizzled by col&7)
          int par = s & 7;
#pragma unroll
          for (int a = 0; a < 2; a++) {
            int r8 = 0;
            r8 = __builtin_amdgcn_cvt_pk_fp8_f32(hv[a * 4 + 0], hv[a * 4 + 1], r8, false);
            r8 = __builtin_amdgcn_cvt_pk_fp8_f32(hv[a * 4 + 2], hv[a * 4 + 3], r8, true);
            *(unsigned int*)(&hb4[par][col * 264 + ((w ^ c7) * 32 + a * 16 + q * 4)]) = (unsigned int)r8;
          }
          lds_barrier();   // lgkmcnt(0)+s_barrier only: no vmcnt drain in the chain
#pragma unroll
          for (int kt = 0; kt < 8; kt++)
            hf8[kt] = *(const long*)(&hb4[par][col * 264 + ((kt ^ c7) * 32 + q * 8)]);

          // batched emission: one wave-pair per buffered step, every 4 steps
          if ((s & 3) == 3 || s == spe - 1) {
            int ebeg = s & ~3;
            int e = ebeg + (w >> 1);
            if (e <= s) {
              f32x4 ea = bo4;
#pragma unroll
              for (int kt = 0; kt < 8; kt++) {
                long hbv = *(const long*)(&hb4[e & 7][col * 264 + ((kt ^ c7) * 32 + q * 8)]);
                ea = __builtin_amdgcn_mfma_f32_16x16x32_fp8_fp8(wo8[kt], hbv, ea, 0, 0, 0);
              }
              if (e < mylen) {
                int pos = dir ? (mylen - 1 - e) : e;
                uint2 pk;
                pk.x = f2bf(ea[0]) | ((unsigned int)f2bf(ea[1]) << 16);
                pk.y = f2bf(ea[2]) | ((unsigned int)f2bf(ea[3]) << 16);
                *(uint2*)(ebase + (((size_t)bcl * 512 + pos) * 32 + (w & 1) * 16 + q * 4)) = pk;
              }
            }
          }
        }
      }
    }
    // consumed chunk c (or never needed it): release parity for chunk c+2
    __syncthreads();
    if (tid == 0)
      __hip_atomic_fetch_add(&flags[512 + c], 1, __ATOMIC_RELEASE, __HIP_MEMORY_SCOPE_AGENT);
  }
}

__global__ __launch_bounds__(512, 2) void fused_persist(
    const float* __restrict__ emb, const int* __restrict__ sent, const int* __restrict__ lens,
    const unsigned short* __restrict__ wih,
    const float* __restrict__ bih_f, const float* __restrict__ bhh_f,
    const float* __restrict__ bih_b, const float* __restrict__ bhh_b,
    unsigned short* __restrict__ gx,
    const unsigned char* __restrict__ whh8, const unsigned char* __restrict__ wout8,
    const float* __restrict__ bout,
    unsigned short* __restrict__ emit_f, unsigned short* __restrict__ emit_b,
    int* flags)
{
  __shared__ __align__(16) unsigned short wtile[128 * 264];
  __shared__ __align__(16) float btile[128];
  __shared__ __align__(16) unsigned char hb4[8][16 * 264];

  if (blockIdx.x < 32) {
    lstm_role(gx, whh8, wout8, bout, lens, emit_f, emit_b, flags, hb4);
  } else {
    gemm_role(emb, sent, lens, wih, bih_f, bhh_f, bih_b, bhh_b, gx, flags, wtile, btile);
  }
}

// ---------------- K3: real-path score + CRF forward (bf16 emit in) ----------------
// 2 sentences per wave: lanes 0-31 = sentence 2b, lanes 32-63 = 2b+1.
// Each half runs a full independent 32-tag scan (no cross-half shfl in chain).
__global__ __launch_bounds__(64) void crf_kernel(
    const unsigned short* __restrict__ emit_f,
    const unsigned short* __restrict__ emit_b,
    const float* __restrict__ trans, const int* __restrict__ tags,
    const int* __restrict__ lens, float* __restrict__ out) {
  const float LOG2E = 1.4426950408889634f, LN2 = 0.6931471805599453f;
  __shared__ __align__(16) float e_lds[2][16384];   // 128 KB: log2e*(emit_f+emit_b)
  int lane = threadIdx.x, half = lane >> 5, j = lane & 31;
  int b0 = blockIdx.x * 2, sb = b0 + half;
  int mylen = lens[sb];

  // ---- stage emit for both sentences (coalesced bf16x8) -> LDS, log2e-scaled ----
#pragma unroll
  for (int ssn = 0; ssn < 2; ssn++) {
    int b = b0 + ssn;
    int ng = lens[b] * 4;                  // groups of 8 bf16
    const unsigned short* pf = emit_f + (size_t)b * 16384;
    const unsigned short* pb = emit_b + (size_t)b * 16384;
    float* dst = e_lds[ssn];
    for (int g = lane; g < ng; g += 64) {
      uint4v fv = *(const uint4v*)(pf + g * 8);
      uint4v bv = *(const uint4v*)(pb + g * 8);
      f32x4 w0, w1;
#pragma unroll
      for (int k = 0; k < 2; k++) {
        w0[2 * k]     = (bf2f(fv[k] & 0xffffu) + bf2f(bv[k] & 0xffffu)) * LOG2E;
        w0[2 * k + 1] = (bf2f(fv[k] >> 16)     + bf2f(bv[k] >> 16))     * LOG2E;
        w1[2 * k]     = (bf2f(fv[k + 2] & 0xffffu) + bf2f(bv[k + 2] & 0xffffu)) * LOG2E;
        w1[2 * k + 1] = (bf2f(fv[k + 2] >> 16)     + bf2f(bv[k + 2] >> 16))     * LOG2E;
      }
      *(f32x4*)(dst + g * 8) = w0;
      *(f32x4*)(dst + g * 8 + 4) = w1;
    }
  }
  __syncthreads();

  // ---- real-path score (own sentence, 32 lanes each) ----
  const int* tg_ = tags + sb * 512;
  float rs2 = 0.f, rst = 0.f;
  for (int s = j; s < mylen; s += 32) {
    int t1 = tg_[s];
    rs2 += e_lds[half][s * 32 + t1];
    if (s > 0) rst += trans[tg_[s - 1] * 32 + t1];
  }
  float rsc = LN2 * rs2 + rst;
#pragma unroll
  for (int m = 16; m; m >>= 1) rsc += __shfl_xor(rsc, m);

  // ---- CRF forward scan, log2 domain, full 32 rows per lane ----
  float tr2[32];
#pragma unroll
  for (int ii = 0; ii < 32; ii++) tr2[ii] = trans[ii * 32 + j] * LOG2E;
  int pb32 = (lane & 32) << 2;          // bpermute byte base of own half
  const float* ep = e_lds[half] + j;
  float B = ep[0];                       // log2-scaled alpha
  float e_nxt = ep[32];                  // len >= 256 always
  for (int s = 1; s < mylen; s++) {
    float e_cur = e_nxt;
    int sn = (s + 1 < mylen) ? (s + 1) : s;
    e_nxt = ep[sn * 32];                 // prefetch next step's emit (LDS)
    float v[32];
#pragma unroll
    for (int ii = 0; ii < 32; ii++)
      v[ii] = __builtin_bit_cast(float, __builtin_amdgcn_ds_bpermute(
                  pb32 + ii * 4, __builtin_bit_cast(int, B))) + tr2[ii];
    // depth-5 max tree (within lane)
    float a16[16], a8[8], a4[4], a2[2];
#pragma unroll
    for (int ii = 0; ii < 16; ii++) a16[ii] = fmaxf(v[ii], v[ii + 16]);
#pragma unroll
    for (int ii = 0; ii < 8; ii++) a8[ii] = fmaxf(a16[ii], a16[ii + 8]);
#pragma unroll
    for (int ii = 0; ii < 4; ii++) a4[ii] = fmaxf(a8[ii], a8[ii + 4]);
    a2[0] = fmaxf(a4[0], a4[2]); a2[1] = fmaxf(a4[1], a4[3]);
    float m1 = fmaxf(a2[0], a2[1]);
    // exp2 + depth-5 sum tree
    float x[32];
#pragma unroll
    for (int ii = 0; ii < 32; ii++) x[ii] = __builtin_amdgcn_exp2f(v[ii] - m1);
    float s16[16], s8[8], s4[4], s2[2];
#pragma unroll
    for (int ii = 0; ii < 16; ii++) s16[ii] = x[ii] + x[ii + 16];
#pragma unroll
    for (int ii = 0; ii < 8; ii++) s8[ii] = s16[ii] + s16[ii + 8];
#pragma unroll
    for (int ii = 0; ii < 4; ii++) s4[ii] = s8[ii] + s8[ii + 4];
    s2[0] = s4[0] + s4[2]; s2[1] = s4[1] + s4[3];
    float sum = s2[0] + s2[1];
    B = m1 + __builtin_amdgcn_logf(sum) + e_cur;   // v_log_f32 = log2
  }
  // log2-sum-exp2 over the 32 tags (within own half)
  float mz = B;
#pragma unroll
  for (int m = 16; m; m >>= 1) mz = fmaxf(mz, __shfl_xor(mz, m));
  float sz = __builtin_amdgcn_exp2f(B - mz);
#pragma unroll
  for (int m = 16; m; m >>= 1) sz += __shfl_xor(sz, m);
  float logz = LN2 * (mz + __builtin_amdgcn_logf(sz));
  if (j == 0) out[sb] = logz - rsc;
}

// ---------------- launch ----------------
extern "C" void kernel_launch(void* const* d_in, const int* in_sizes, int n_in,
                              void* d_out, int out_size, void* d_ws, size_t ws_size,
                              hipStream_t stream) {
  const float* emb   = (const float*)d_in[0];
  const float* Wih_f = (const float*)d_in[1];
  const float* Whh_f = (const float*)d_in[2];
  const float* bih_f = (const float*)d_in[3];
  const float* bhh_f = (const float*)d_in[4];
  const float* Wih_b = (const float*)d_in[5];
  const float* Whh_b = (const float*)d_in[6];
  const float* bih_b = (const float*)d_in[7];
  const float* bhh_b = (const float*)d_in[8];
  const float* Wout  = (const float*)d_in[9];
  const float* bout  = (const float*)d_in[10];
  const float* trans = (const float*)d_in[11];
  const int* sent = (const int*)d_in[12];
  const int* tags = (const int*)d_in[13];
  const int* lens = (const int*)d_in[14];
  float* out = (float*)d_out;

  // workspace layout (bytes), total 87,048,192
  char* ws = (char*)d_ws;
  if (ws_size < 87048192ull) return;
  unsigned short* gx      = (unsigned short*)(ws);                // 67,108,864 (2 parity x 32s)
  unsigned short* emit_f  = (unsigned short*)(ws + 67108864);     //  8,388,608
  unsigned short* emit_b  = (unsigned short*)(ws + 75497472);     //  8,388,608
  unsigned short* wih_bf  = (unsigned short*)(ws + 83886080);     //  1,048,576
  unsigned char*  whh8    = (unsigned char*)(ws + 84934656);      //    524,288
  unsigned char*  wout8   = (unsigned char*)(ws + 85458944);      //     16,384
  int*            flags   = (int*)(ws + 85475328);                //  2,176 (ready+done)

  cvt_weights<<<1040, 256, 0, stream>>>(Wih_f, Wih_b, Whh_f, Whh_b, Wout,
                                        wih_bf, whh8, wout8, flags);
  fused_persist<<<256, 512, 0, stream>>>(
      emb, sent, lens, wih_bf, bih_f, bhh_f, bih_b, bhh_b, gx,
      whh8, wout8, bout, emit_f, emit_b, flags);
  crf_kernel<<<128, 64, 0, stream>>>(emit_f, emit_b, trans, tags, lens, out);
}

// Round 6
// 1680.517 us; speedup vs baseline: 1.0263x; 1.0263x over previous
//
#include <hip/hip_runtime.h>
#include <hip/hip_bf16.h>

// BiLSTM-CRF forward, MI355X gfx950.
// B=256, S=512, E=256, H=256, G=4H=1024, T=32, PAD=49999.
//
// Round-13 = round-11/4 fused pipeline (proven 1343us steady) + 2-sent/wave crf.
//   fused_persist, grid 256 x 512thr (1 block/CU):
//     blocks 0..31  : persistent LSTM, 16 owned sentences each. h/c + W_hh(fp8)
//                     + W_out frags VGPR/AGPR-resident all 512 steps. Per-step h
//                     exchange via raw s_barrier+lgkmcnt; emission batched /4 steps.
//     blocks 32..255: 224 gemm workers, tiles ss-major, fine-grained span flags.
//   crf_kernel: 128 blocks, 2 sentences per wave (independent 32-tag scan per
//   32-lane half, no cross-half shfl in the serial chain).

typedef __bf16 bf16x8 __attribute__((ext_vector_type(8)));
typedef float f32x4 __attribute__((ext_vector_type(4)));
typedef unsigned int uint4v __attribute__((ext_vector_type(4)));

__device__ __forceinline__ unsigned short f2bf(float f) {
  union { float f; unsigned int u; } v; v.f = f;
  unsigned int r = v.u + 0x7fffu + ((v.u >> 16) & 1u);   // RNE
  return (unsigned short)(r >> 16);
}
__device__ __forceinline__ float bf2f(unsigned int lo16) {
  union { unsigned int u; float f; } v; v.u = lo16 << 16;
  return v.f;
}
__device__ __forceinline__ float fsig(float x) {
  float e = __builtin_amdgcn_exp2f(-1.4426950408889634f * x);
  return __builtin_amdgcn_rcpf(1.0f + e);
}
__device__ __forceinline__ float ftanh(float x) {
  float e = __builtin_amdgcn_exp2f(2.8853900817779268f * x);
  return 1.0f - 2.0f * __builtin_amdgcn_rcpf(e + 1.0f);
}

__device__ __forceinline__ void wait_ge(int* p, int target) {
  if (threadIdx.x == 0) {
    while (__hip_atomic_load(p, __ATOMIC_RELAXED, __HIP_MEMORY_SCOPE_AGENT) < target)
      __builtin_amdgcn_s_sleep(2);
    (void)__hip_atomic_load(p, __ATOMIC_ACQUIRE, __HIP_MEMORY_SCOPE_AGENT);
  }
  __syncthreads();
}

// LDS-only barrier: no vmcnt(0) drain (keeps emission stores / gx prefetch
// loads in flight across the per-step h exchange).
__device__ __forceinline__ void lds_barrier() {
  asm volatile("s_waitcnt lgkmcnt(0)\n\ts_barrier" ::: "memory");
}

// ---------------- K0: weight conversion + flag reset ----------------
__global__ void cvt_weights(const float* __restrict__ wih_f, const float* __restrict__ wih_b,
                            const float* __restrict__ whh_f, const float* __restrict__ whh_b,
                            const float* __restrict__ wo,
                            unsigned short* __restrict__ wih,    // bf16 [2][1024][256]
                            unsigned char* __restrict__ whh8,    // fp8  [2][1024][256]
                            unsigned char* __restrict__ wout8,   // fp8  [32][512]
                            int* __restrict__ flags) {           // ready[512] + done[16]
  if (blockIdx.x == 0) {
    for (int f = threadIdx.x; f < 544; f += 256) flags[f] = 0;
  }
  int t = blockIdx.x * 256 + threadIdx.x;
  int i = t * 4;
  if (i < 524288) {
    const float* src = (i < 262144) ? wih_f : wih_b;
    f32x4 v = *(const f32x4*)(src + (i & 262143));
    uint2 p;
    p.x = f2bf(v[0]) | ((unsigned int)f2bf(v[1]) << 16);
    p.y = f2bf(v[2]) | ((unsigned int)f2bf(v[3]) << 16);
    *(uint2*)(wih + i) = p;
  } else if (i < 1048576) {
    int k = i - 524288;
    const float* src = (k < 262144) ? whh_f : whh_b;
    f32x4 v = *(const f32x4*)(src + (k & 262143));
    int r = 0;
    r = __builtin_amdgcn_cvt_pk_fp8_f32(v[0], v[1], r, false);
    r = __builtin_amdgcn_cvt_pk_fp8_f32(v[2], v[3], r, true);
    *(unsigned int*)(whh8 + k) = (unsigned int)r;
  } else if (i < 1064960) {
    int k = i - 1048576;
    f32x4 v = *(const f32x4*)(wo + k);
    int r = 0;
    r = __builtin_amdgcn_cvt_pk_fp8_f32(v[0], v[1], r, false);
    r = __builtin_amdgcn_cvt_pk_fp8_f32(v[2], v[3], r, true);
    *(unsigned int*)(wout8 + k) = (unsigned int)r;
  }
}

// ---------------- persistent roles ----------------
// gx layout: [parity][dir][32 s][256 b][1024 g] bf16
//   parity stride 16,777,216 elems; dir 8,388,608; s 262,144.
// flags: ready[k*32 + ss*8 + dir*4 + bt] (target 8 = nc tiles), done[512 + k]
//   (target 32 = lstm blocks).

__device__ void gemm_role(
    const float* __restrict__ emb, const int* __restrict__ sent, const int* __restrict__ lens,
    const unsigned short* __restrict__ wih,
    const float* __restrict__ bih_f, const float* __restrict__ bhh_f,
    const float* __restrict__ bih_b, const float* __restrict__ bhh_b,
    unsigned short* __restrict__ gx, int* flags,
    unsigned short* wtile, float* btile)
{
  int gb = blockIdx.x - 32;   // 0..223
  int tid = threadIdx.x, w = tid >> 6, lane = tid & 63, col = lane & 15, q = lane >> 4;
  int ns = w >> 2, cg = w & 3;
  int prev_chunk = -1;

  for (int idx = gb; idx < 4096; idx += 224) {
    int k = idx >> 8, t = idx & 255;
    // ss-major within chunk: early s-spans produced first
    int ss = t >> 6, rest = t & 63;
    int dir = (rest >> 5) & 1, nc = (rest >> 2) & 7, bt = rest & 3;
    if (k != prev_chunk) {
      prev_chunk = k;
      if (k >= 2) wait_ge(&flags[512 + k - 2], 32);   // parity reuse backpressure
    }
    int n0 = nc * 128, bbase = bt * 64;
    int sbase = k * 32 + ss * 8;

    if (sbase < lens[bbase]) {   // sorted desc: lens[bbase] = tile max
      const unsigned short* wsrc = wih + (size_t)dir * 262144;
#pragma unroll
      for (int it = 0; it < 8; it++) {
        int seg = it * 512 + tid;
        int row = seg >> 5, kc = (seg & 31) * 8;
        *(uint4v*)(wtile + row * 264 + kc) = *(const uint4v*)(wsrc + (size_t)(n0 + row) * 256 + kc);
      }
      const float* bi = dir ? bih_b : bih_f;
      const float* bh = dir ? bhh_b : bhh_f;
      if (tid < 128) btile[tid] = bi[n0 + tid] + bh[n0 + tid];
      __syncthreads();

      bf16x8 wf[8][4];
#pragma unroll
      for (int kt = 0; kt < 8; kt++)
#pragma unroll
        for (int nt = 0; nt < 4; nt++)
          wf[kt][nt] = *(const bf16x8*)(wtile + (ns * 64 + nt * 16 + col) * 264 + kt * 32 + q * 8);
      f32x4 bias[4];
#pragma unroll
      for (int nt = 0; nt < 4; nt++)
#pragma unroll
        for (int rr = 0; rr < 4; rr++)
          bias[nt][rr] = btile[ns * 64 + nt * 16 + q * 4 + rr];

      int bidx = bbase + cg * 16 + col;
      int len = lens[bidx];
      const int* srow = sent + bidx * 512;

      for (int i = 0; i < 8; i++) {
        int s = sbase + i;
        int s_eff = dir ? ((s < len) ? (len - 1 - s) : s) : s;
        int token = srow[s_eff];
        const float* ep = emb + (size_t)token * 256;
        bf16x8 xf[8];
#pragma unroll
        for (int kt = 0; kt < 8; kt++) {
          f32x4 a0 = *(const f32x4*)(ep + kt * 32 + q * 8);
          f32x4 a1 = *(const f32x4*)(ep + kt * 32 + q * 8 + 4);
          uint4v pk;
          pk[0] = f2bf(a0[0]) | ((unsigned int)f2bf(a0[1]) << 16);
          pk[1] = f2bf(a0[2]) | ((unsigned int)f2bf(a0[3]) << 16);
          pk[2] = f2bf(a1[0]) | ((unsigned int)f2bf(a1[1]) << 16);
          pk[3] = f2bf(a1[2]) | ((unsigned int)f2bf(a1[3]) << 16);
          xf[kt] = __builtin_bit_cast(bf16x8, pk);
        }
        f32x4 acc[4];
#pragma unroll
        for (int nt = 0; nt < 4; nt++) acc[nt] = bias[nt];
#pragma unroll
        for (int kt = 0; kt < 8; kt++)
#pragma unroll
          for (int nt = 0; nt < 4; nt++)
            acc[nt] = __builtin_amdgcn_mfma_f32_16x16x32_bf16(wf[kt][nt], xf[kt], acc[nt], 0, 0, 0);
        size_t off = (size_t)(k & 1) * 16777216 + (size_t)dir * 8388608
                   + (size_t)(s - k * 32) * 262144 + (size_t)bidx * 1024 + n0 + ns * 64;
#pragma unroll
        for (int nt = 0; nt < 4; nt++) {
          uint2 pk;
          pk.x = f2bf(acc[nt][0]) | ((unsigned int)f2bf(acc[nt][1]) << 16);
          pk.y = f2bf(acc[nt][2]) | ((unsigned int)f2bf(acc[nt][3]) << 16);
          *(uint2*)(gx + off + nt * 16 + q * 4) = pk;
        }
      }
    }
    // tile done: barrier drains this block's gx stores, then device-scope release
    __syncthreads();
    if (tid == 0)
      __hip_atomic_fetch_add(&flags[k * 32 + ss * 8 + dir * 4 + bt], 1,
                             __ATOMIC_RELEASE, __HIP_MEMORY_SCOPE_AGENT);
  }
}

__device__ void lstm_role(
    const unsigned short* __restrict__ gx,
    const unsigned char* __restrict__ whh8,
    const unsigned char* __restrict__ wout8,
    const float* __restrict__ bout,
    const int* __restrict__ lens,
    unsigned short* __restrict__ emit_f, unsigned short* __restrict__ emit_b,
    int* flags, unsigned char (*hb4)[16 * 264])
{
  int bx = blockIdx.x;                 // 0..31
  int dir = bx & 1, grp = bx >> 1, b0 = grp * 16;
  int bt = grp >> 2;                   // gemm sentence-tile group (64 sentences)
  int tid = threadIdx.x, w = tid >> 6, lane = tid & 63, col = lane & 15, q = lane >> 4;
  int maxlen = lens[b0];               // sorted desc
  int bcl = b0 + col;                  // owned sentence (all 16 cols real)
  int mylen = lens[bcl];

  // ---- W_hh fp8 fragments fully into registers/AGPRs (64 x 8B), once ----
  const unsigned char* whb = whh8 + (size_t)dir * 262144;
  long wh[8][8];
#pragma unroll
  for (int kt = 0; kt < 8; kt++)
#pragma unroll
    for (int t = 0; t < 8; t++) {
      int row0 = (t & 3) * 256 + w * 32 + (t >> 2) * 16;
      wh[kt][t] = *(const long*)(whb + (size_t)(row0 + col) * 256 + kt * 32 + q * 8);
    }

  // ---- emission weights fp8: every wave holds tag-half (w&1)*16 ----
  long wo8[8];
  f32x4 bo4 = (f32x4){0.f, 0.f, 0.f, 0.f};
#pragma unroll
  for (int kt = 0; kt < 8; kt++)
    wo8[kt] = *(const long*)(wout8 + (size_t)((w & 1) * 16 + col) * 512 + dir * 256 + kt * 32 + q * 8);
  if (dir == 0) {
#pragma unroll
    for (int r = 0; r < 4; r++) bo4[r] = bout[(w & 1) * 16 + q * 4 + r];
  }
  unsigned short* ebase = dir ? emit_b : emit_f;

  // ---- persistent state (registers, whole sequence) ----
  float c8[8];
  long hf8[8];
#pragma unroll
  for (int i = 0; i < 8; i++) { c8[i] = 0.f; hf8[i] = 0; }

  for (int c = 0; c < 16; c++) {
    int s0 = c * 32;
    if (s0 < maxlen) {
      int cend = s0 + 32; if (cend > maxlen) cend = maxlen;
      const unsigned short* gbase = gx + (size_t)(c & 1) * 16777216 + (size_t)dir * 8388608
                                       + (size_t)bcl * 1024 + q * 4;
      for (int ss = 0; ss < 4; ss++) {
        int sp0 = s0 + ss * 8;
        if (sp0 >= maxlen) break;
        int spe = sp0 + 8; if (spe > cend) spe = cend;
        wait_ge(&flags[c * 32 + ss * 8 + dir * 4 + bt], 8);   // span produced

        uint2 gxr[8];
        {
          const unsigned short* gf = gbase + (size_t)(sp0 - s0) * 262144;
#pragma unroll
          for (int t = 0; t < 8; t++) {
            int row0 = (t & 3) * 256 + w * 32 + (t >> 2) * 16;
            gxr[t] = *(const uint2*)(gf + row0);
          }
        }

        for (int s = sp0; s < spe; s++) {
          f32x4 acc[8];
#pragma unroll
          for (int t = 0; t < 8; t++) {
            f32x4 a;
            a[0] = bf2f(gxr[t].x & 0xffffu); a[1] = bf2f(gxr[t].x >> 16);
            a[2] = bf2f(gxr[t].y & 0xffffu); a[3] = bf2f(gxr[t].y >> 16);
            acc[t] = a;
          }
          // prefetch gx for s+1 (within span only; span boundary reloads fresh)
          if (s + 1 < spe) {
            const unsigned short* gn = gbase + (size_t)(s + 1 - s0) * 262144;
#pragma unroll
            for (int t = 0; t < 8; t++) {
              int row0 = (t & 3) * 256 + w * 32 + (t >> 2) * 16;
              gxr[t] = *(const uint2*)(gn + row0);
            }
          }
          // h-part: fp8 MFMA, W resident
#pragma unroll
          for (int kt = 0; kt < 8; kt++) {
            long hv8 = hf8[kt];
#pragma unroll
            for (int t = 0; t < 8; t++)
              acc[t] = __builtin_amdgcn_mfma_f32_16x16x32_fp8_fp8(wh[kt][t], hv8, acc[t], 0, 0, 0);
          }
          // gates
          float hv[8];
#pragma unroll
          for (int a = 0; a < 2; a++)
#pragma unroll
            for (int r = 0; r < 4; r++) {
              float ig = acc[a * 4 + 0][r], fg = acc[a * 4 + 1][r];
              float gg = acc[a * 4 + 2][r], og = acc[a * 4 + 3][r];
              float cn = fsig(fg) * c8[a * 4 + r] + fsig(ig) * ftanh(gg);
              c8[a * 4 + r] = cn;
              hv[a * 4 + r] = fsig(og) * ftanh(cn);
            }
          // write fp8 h to 8-deep LDS history
          int par = s & 7;
#pragma unroll
          for (int a = 0; a < 2; a++) {
            int r8 = 0;
            r8 = __builtin_amdgcn_cvt_pk_fp8_f32(hv[a * 4 + 0], hv[a * 4 + 1], r8, false);
            r8 = __builtin_amdgcn_cvt_pk_fp8_f32(hv[a * 4 + 2], hv[a * 4 + 3], r8, true);
            *(unsigned int*)(&hb4[par][col * 264 + w * 32 + a * 16 + q * 4]) = (unsigned int)r8;
          }
          lds_barrier();   // lgkmcnt(0)+s_barrier only: no vmcnt drain in the chain
#pragma unroll
          for (int kt = 0; kt < 8; kt++)
            hf8[kt] = *(const long*)(&hb4[par][col * 264 + kt * 32 + q * 8]);

          // batched emission: one wave-pair per buffered step, every 4 steps
          if ((s & 3) == 3 || s == spe - 1) {
            int ebeg = s & ~3;
            int e = ebeg + (w >> 1);
            if (e <= s) {
              f32x4 ea = bo4;
#pragma unroll
              for (int kt = 0; kt < 8; kt++) {
                long hbv = *(const long*)(&hb4[e & 7][col * 264 + kt * 32 + q * 8]);
                ea = __builtin_amdgcn_mfma_f32_16x16x32_fp8_fp8(wo8[kt], hbv, ea, 0, 0, 0);
              }
              if (e < mylen) {
                int pos = dir ? (mylen - 1 - e) : e;
                uint2 pk;
                pk.x = f2bf(ea[0]) | ((unsigned int)f2bf(ea[1]) << 16);
                pk.y = f2bf(ea[2]) | ((unsigned int)f2bf(ea[3]) << 16);
                *(uint2*)(ebase + (((size_t)bcl * 512 + pos) * 32 + (w & 1) * 16 + q * 4)) = pk;
              }
            }
          }
        }
      }
    }
    // consumed chunk c (or never needed it): release parity for chunk c+2
    __syncthreads();
    if (tid == 0)
      __hip_atomic_fetch_add(&flags[512 + c], 1, __ATOMIC_RELEASE, __HIP_MEMORY_SCOPE_AGENT);
  }
}

__global__ __launch_bounds__(512, 2) void fused_persist(
    const float* __restrict__ emb, const int* __restrict__ sent, const int* __restrict__ lens,
    const unsigned short* __restrict__ wih,
    const float* __restrict__ bih_f, const float* __restrict__ bhh_f,
    const float* __restrict__ bih_b, const float* __restrict__ bhh_b,
    unsigned short* __restrict__ gx,
    const unsigned char* __restrict__ whh8, const unsigned char* __restrict__ wout8,
    const float* __restrict__ bout,
    unsigned short* __restrict__ emit_f, unsigned short* __restrict__ emit_b,
    int* flags)
{
  __shared__ __align__(16) unsigned short wtile[128 * 264];
  __shared__ __align__(16) float btile[128];
  __shared__ __align__(16) unsigned char hb4[8][16 * 264];

  if (blockIdx.x < 32) {
    lstm_role(gx, whh8, wout8, bout, lens, emit_f, emit_b, flags, hb4);
  } else {
    gemm_role(emb, sent, lens, wih, bih_f, bhh_f, bih_b, bhh_b, gx, flags, wtile, btile);
  }
}

// ---------------- K3: real-path score + CRF forward (bf16 emit in) ----------------
// 2 sentences per wave: lanes 0-31 = sentence 2b, lanes 32-63 = 2b+1.
// Each half runs a full independent 32-tag scan (no cross-half shfl in chain).
__global__ __launch_bounds__(64) void crf_kernel(
    const unsigned short* __restrict__ emit_f,
    const unsigned short* __restrict__ emit_b,
    const float* __restrict__ trans, const int* __restrict__ tags,
    const int* __restrict__ lens, float* __restrict__ out) {
  const float LOG2E = 1.4426950408889634f, LN2 = 0.6931471805599453f;
  __shared__ __align__(16) float e_lds[2][16384];   // 128 KB: log2e*(emit_f+emit_b)
  int lane = threadIdx.x, half = lane >> 5, j = lane & 31;
  int b0 = blockIdx.x * 2, sb = b0 + half;
  int mylen = lens[sb];

  // ---- stage emit for both sentences (coalesced bf16x8) -> LDS, log2e-scaled ----
#pragma unroll
  for (int ssn = 0; ssn < 2; ssn++) {
    int b = b0 + ssn;
    int ng = lens[b] * 4;                  // groups of 8 bf16
    const unsigned short* pf = emit_f + (size_t)b * 16384;
    const unsigned short* pb = emit_b + (size_t)b * 16384;
    float* dst = e_lds[ssn];
    for (int g = lane; g < ng; g += 64) {
      uint4v fv = *(const uint4v*)(pf + g * 8);
      uint4v bv = *(const uint4v*)(pb + g * 8);
      f32x4 w0, w1;
#pragma unroll
      for (int k = 0; k < 2; k++) {
        w0[2 * k]     = (bf2f(fv[k] & 0xffffu) + bf2f(bv[k] & 0xffffu)) * LOG2E;
        w0[2 * k + 1] = (bf2f(fv[k] >> 16)     + bf2f(bv[k] >> 16))     * LOG2E;
        w1[2 * k]     = (bf2f(fv[k + 2] & 0xffffu) + bf2f(bv[k + 2] & 0xffffu)) * LOG2E;
        w1[2 * k + 1] = (bf2f(fv[k + 2] >> 16)     + bf2f(bv[k + 2] >> 16))     * LOG2E;
      }
      *(f32x4*)(dst + g * 8) = w0;
      *(f32x4*)(dst + g * 8 + 4) = w1;
    }
  }
  __syncthreads();

  // ---- real-path score (own sentence, 32 lanes each) ----
  const int* tg_ = tags + sb * 512;
  float rs2 = 0.f, rst = 0.f;
  for (int s = j; s < mylen; s += 32) {
    int t1 = tg_[s];
    rs2 += e_lds[half][s * 32 + t1];
    if (s > 0) rst += trans[tg_[s - 1] * 32 + t1];
  }
  float rsc = LN2 * rs2 + rst;
#pragma unroll
  for (int m = 16; m; m >>= 1) rsc += __shfl_xor(rsc, m);

  // ---- CRF forward scan, log2 domain, full 32 rows per lane ----
  float tr2[32];
#pragma unroll
  for (int ii = 0; ii < 32; ii++) tr2[ii] = trans[ii * 32 + j] * LOG2E;
  int pb32 = (lane & 32) << 2;          // bpermute byte base of own half
  const float* ep = e_lds[half] + j;
  float B = ep[0];                       // log2-scaled alpha
  float e_nxt = ep[32];                  // len >= 256 always
  for (int s = 1; s < mylen; s++) {
    float e_cur = e_nxt;
    int sn = (s + 1 < mylen) ? (s + 1) : s;
    e_nxt = ep[sn * 32];                 // prefetch next step's emit (LDS)
    float v[32];
#pragma unroll
    for (int ii = 0; ii < 32; ii++)
      v[ii] = __builtin_bit_cast(float, __builtin_amdgcn_ds_bpermute(
                  pb32 + ii * 4, __builtin_bit_cast(int, B))) + tr2[ii];
    // depth-5 max tree (within lane)
    float a16[16], a8[8], a4[4], a2[2];
#pragma unroll
    for (int ii = 0; ii < 16; ii++) a16[ii] = fmaxf(v[ii], v[ii + 16]);
#pragma unroll
    for (int ii = 0; ii < 8; ii++) a8[ii] = fmaxf(a16[ii], a16[ii + 8]);
#pragma unroll
    for (int ii = 0; ii < 4; ii++) a4[ii] = fmaxf(a8[ii], a8[ii + 4]);
    a2[0] = fmaxf(a4[0], a4[2]); a2[1] = fmaxf(a4[1], a4[3]);
    float m1 = fmaxf(a2[0], a2[1]);
    // exp2 + depth-5 sum tree
    float x[32];
#pragma unroll
    for (int ii = 0; ii < 32; ii++) x[ii] = __builtin_amdgcn_exp2f(v[ii] - m1);
    float s16[16], s8[8], s4[4], s2[2];
#pragma unroll
    for (int ii = 0; ii < 16; ii++) s16[ii] = x[ii] + x[ii + 16];
#pragma unroll
    for (int ii = 0; ii < 8; ii++) s8[ii] = s16[ii] + s16[ii + 8];
#pragma unroll
    for (int ii = 0; ii < 4; ii++) s4[ii] = s8[ii] + s8[ii + 4];
    s2[0] = s4[0] + s4[2]; s2[1] = s4[1] + s4[3];
    float sum = s2[0] + s2[1];
    B = m1 + __builtin_amdgcn_logf(sum) + e_cur;   // v_log_f32 = log2
  }
  // log2-sum-exp2 over the 32 tags (within own half)
  float mz = B;
#pragma unroll
  for (int m = 16; m; m >>= 1) mz = fmaxf(mz, __shfl_xor(mz, m));
  float sz = __builtin_amdgcn_exp2f(B - mz);
#pragma unroll
  for (int m = 16; m; m >>= 1) sz += __shfl_xor(sz, m);
  float logz = LN2 * (mz + __builtin_amdgcn_logf(sz));
  if (j == 0) out[sb] = logz - rsc;
}

// ---------------- launch ----------------
extern "C" void kernel_launch(void* const* d_in, const int* in_sizes, int n_in,
                              void* d_out, int out_size, void* d_ws, size_t ws_size,
                              hipStream_t stream) {
  const float* emb   = (const float*)d_in[0];
  const float* Wih_f = (const float*)d_in[1];
  const float* Whh_f = (const float*)d_in[2];
  const float* bih_f = (const float*)d_in[3];
  const float* bhh_f = (const float*)d_in[4];
  const float* Wih_b = (const float*)d_in[5];
  const float* Whh_b = (const float*)d_in[6];
  const float* bih_b = (const float*)d_in[7];
  const float* bhh_b = (const float*)d_in[8];
  const float* Wout  = (const float*)d_in[9];
  const float* bout  = (const float*)d_in[10];
  const float* trans = (const float*)d_in[11];
  const int* sent = (const int*)d_in[12];
  const int* tags = (const int*)d_in[13];
  const int* lens = (const int*)d_in[14];
  float* out = (float*)d_out;

  // workspace layout (bytes), total 87,048,192
  char* ws = (char*)d_ws;
  if (ws_size < 87048192ull) return;
  unsigned short* gx      = (unsigned short*)(ws);                // 67,108,864 (2 parity x 32s)
  unsigned short* emit_f  = (unsigned short*)(ws + 67108864);     //  8,388,608
  unsigned short* emit_b  = (unsigned short*)(ws + 75497472);     //  8,388,608
  unsigned short* wih_bf  = (unsigned short*)(ws + 83886080);     //  1,048,576
  unsigned char*  whh8    = (unsigned char*)(ws + 84934656);      //    524,288
  unsigned char*  wout8   = (unsigned char*)(ws + 85458944);      //     16,384
  int*            flags   = (int*)(ws + 85475328);                //  2,176 (ready+done)

  cvt_weights<<<1040, 256, 0, stream>>>(Wih_f, Wih_b, Whh_f, Whh_b, Wout,
                                        wih_bf, whh8, wout8, flags);
  fused_persist<<<256, 512, 0, stream>>>(
      emb, sent, lens, wih_bf, bih_f, bhh_f, bih_b, bhh_b, gx,
      whh8, wout8, bout, emit_f, emit_b, flags);
  crf_kernel<<<128, 64, 0, stream>>>(emit_f, emit_b, trans, tags, lens, out);
}

// Round 7
// 1526.214 us; speedup vs baseline: 1.1301x; 1.1011x over previous
//
#include <hip/hip_runtime.h>
#include <hip/hip_bf16.h>

// BiLSTM-CRF forward, MI355X gfx950.
// B=256, S=512, E=256, H=256, G=4H=1024, T=32, PAD=49999.
//
// Round-14: gemm restructured to kill redundant embedding gather.
//   Tile = ALL 1024 gates x 16 sentences x 8 steps. Block gathers the 128 emb
//   rows ONCE (f32->bf16) into an LDS x-tile, streams W_ih bf16 from L2, and
//   runs 512 MFMA/wave. Gather traffic drops 8x (2GB -> 256MB/iter).
//   128 tiles/chunk over 224 workers (<1 pass). Single-producer ready flags
//   per (chunk, span, dir, sg). lstm role unchanged (flag index only).
//   crf reverted to 1-sentence/block (256 blocks) - the 2-sent variant halved
//   wave count in a latency-bound regime and doubled wall time.

typedef __bf16 bf16x8 __attribute__((ext_vector_type(8)));
typedef float f32x4 __attribute__((ext_vector_type(4)));
typedef unsigned int uint4v __attribute__((ext_vector_type(4)));

__device__ __forceinline__ unsigned short f2bf(float f) {
  union { float f; unsigned int u; } v; v.f = f;
  unsigned int r = v.u + 0x7fffu + ((v.u >> 16) & 1u);   // RNE
  return (unsigned short)(r >> 16);
}
__device__ __forceinline__ float bf2f(unsigned int lo16) {
  union { unsigned int u; float f; } v; v.u = lo16 << 16;
  return v.f;
}
__device__ __forceinline__ float fsig(float x) {
  float e = __builtin_amdgcn_exp2f(-1.4426950408889634f * x);
  return __builtin_amdgcn_rcpf(1.0f + e);
}
__device__ __forceinline__ float ftanh(float x) {
  float e = __builtin_amdgcn_exp2f(2.8853900817779268f * x);
  return 1.0f - 2.0f * __builtin_amdgcn_rcpf(e + 1.0f);
}

__device__ __forceinline__ void wait_ge(int* p, int target) {
  if (threadIdx.x == 0) {
    while (__hip_atomic_load(p, __ATOMIC_RELAXED, __HIP_MEMORY_SCOPE_AGENT) < target)
      __builtin_amdgcn_s_sleep(2);
    (void)__hip_atomic_load(p, __ATOMIC_ACQUIRE, __HIP_MEMORY_SCOPE_AGENT);
  }
  __syncthreads();
}

// LDS-only barrier: no vmcnt(0) drain (keeps emission stores / gx prefetch
// loads in flight across the per-step h exchange).
__device__ __forceinline__ void lds_barrier() {
  asm volatile("s_waitcnt lgkmcnt(0)\n\ts_barrier" ::: "memory");
}

// ---------------- K0: weight conversion + flag reset ----------------
__global__ void cvt_weights(const float* __restrict__ wih_f, const float* __restrict__ wih_b,
                            const float* __restrict__ whh_f, const float* __restrict__ whh_b,
                            const float* __restrict__ wo,
                            unsigned short* __restrict__ wih,    // bf16 [2][1024][256]
                            unsigned char* __restrict__ whh8,    // fp8  [2][1024][256]
                            unsigned char* __restrict__ wout8,   // fp8  [32][512]
                            int* __restrict__ flags) {           // ready[2048] + done[16]
  if (blockIdx.x == 0) {
    for (int f = threadIdx.x; f < 2080; f += 256) flags[f] = 0;
  }
  int t = blockIdx.x * 256 + threadIdx.x;
  int i = t * 4;
  if (i < 524288) {
    const float* src = (i < 262144) ? wih_f : wih_b;
    f32x4 v = *(const f32x4*)(src + (i & 262143));
    uint2 p;
    p.x = f2bf(v[0]) | ((unsigned int)f2bf(v[1]) << 16);
    p.y = f2bf(v[2]) | ((unsigned int)f2bf(v[3]) << 16);
    *(uint2*)(wih + i) = p;
  } else if (i < 1048576) {
    int k = i - 524288;
    const float* src = (k < 262144) ? whh_f : whh_b;
    f32x4 v = *(const f32x4*)(src + (k & 262143));
    int r = 0;
    r = __builtin_amdgcn_cvt_pk_fp8_f32(v[0], v[1], r, false);
    r = __builtin_amdgcn_cvt_pk_fp8_f32(v[2], v[3], r, true);
    *(unsigned int*)(whh8 + k) = (unsigned int)r;
  } else if (i < 1064960) {
    int k = i - 1048576;
    f32x4 v = *(const f32x4*)(wo + k);
    int r = 0;
    r = __builtin_amdgcn_cvt_pk_fp8_f32(v[0], v[1], r, false);
    r = __builtin_amdgcn_cvt_pk_fp8_f32(v[2], v[3], r, true);
    *(unsigned int*)(wout8 + k) = (unsigned int)r;
  }
}

// ---------------- persistent roles ----------------
// gx layout: [parity][dir][32 s][256 b][1024 g] bf16
//   parity stride 16,777,216 elems; dir 8,388,608; s 262,144.
// flags: ready[k*128 + ss*32 + dir*16 + sg] (target 1, single producer),
//        done[2048 + k] (target 32 = lstm blocks).

__device__ void gemm_role(
    const float* __restrict__ emb, const int* __restrict__ sent, const int* __restrict__ lens,
    const unsigned short* __restrict__ wih,
    const float* __restrict__ bih_f, const float* __restrict__ bhh_f,
    const float* __restrict__ bih_b, const float* __restrict__ bhh_b,
    unsigned short* __restrict__ gx, int* flags,
    unsigned short* xtile,      // [128][264] bf16 (row = st*16 + si)
    float* btile)               // [1024]
{
  int gb = blockIdx.x - 32;   // 0..223
  int tid = threadIdx.x, w = tid >> 6, lane = tid & 63, col = lane & 15, q = lane >> 4;
  int prev_chunk = -1;

  for (int idx = gb; idx < 2048; idx += 224) {
    int k = idx >> 7, t = idx & 127;
    int ss = t >> 5, dir = (t >> 4) & 1, sg = t & 15;
    if (k != prev_chunk) {
      prev_chunk = k;
      if (k >= 2) wait_ge(&flags[2048 + k - 2], 32);   // parity reuse backpressure
    }
    int b0 = sg * 16;
    int sbase = k * 32 + ss * 8;

    if (sbase < lens[b0]) {   // sorted desc: lens[b0] = group max
      // ---- stage x: 128 emb rows (16 sent x 8 steps) -> bf16 LDS, once ----
      {
        int r = tid >> 2, t4 = tid & 3;       // 4 threads per row, 64 f32 each
        int st = r >> 4, si = r & 15;
        int bidx = b0 + si;
        int len = lens[bidx];
        int s = sbase + st;
        int s_eff = dir ? ((s < len) ? (len - 1 - s) : s) : s;
        int token = sent[bidx * 512 + s_eff];
        const float* ep = emb + (size_t)token * 256 + t4 * 64;
        unsigned short* xd = xtile + r * 264 + t4 * 64;
#pragma unroll
        for (int u = 0; u < 4; u++) {
          f32x4 a0 = *(const f32x4*)(ep + u * 16);
          f32x4 a1 = *(const f32x4*)(ep + u * 16 + 4);
          f32x4 a2 = *(const f32x4*)(ep + u * 16 + 8);
          f32x4 a3 = *(const f32x4*)(ep + u * 16 + 12);
          uint4v p0, p1;
          p0[0] = f2bf(a0[0]) | ((unsigned int)f2bf(a0[1]) << 16);
          p0[1] = f2bf(a0[2]) | ((unsigned int)f2bf(a0[3]) << 16);
          p0[2] = f2bf(a1[0]) | ((unsigned int)f2bf(a1[1]) << 16);
          p0[3] = f2bf(a1[2]) | ((unsigned int)f2bf(a1[3]) << 16);
          p1[0] = f2bf(a2[0]) | ((unsigned int)f2bf(a2[1]) << 16);
          p1[1] = f2bf(a2[2]) | ((unsigned int)f2bf(a2[3]) << 16);
          p1[2] = f2bf(a3[0]) | ((unsigned int)f2bf(a3[1]) << 16);
          p1[3] = f2bf(a3[2]) | ((unsigned int)f2bf(a3[3]) << 16);
          *(uint4v*)(xd + u * 16) = p0;
          *(uint4v*)(xd + u * 16 + 8) = p1;
        }
        const float* bi = dir ? bih_b : bih_f;
        const float* bh = dir ? bhh_b : bhh_f;
        btile[tid] = bi[tid] + bh[tid];
        btile[tid + 512] = bi[tid + 512] + bh[tid + 512];
      }
      __syncthreads();

      // ---- compute: wave w -> gates [w*128, w*128+128), 2 blocks of 64 ----
      const unsigned short* wsrc = wih + (size_t)dir * 262144;
#pragma unroll
      for (int ntb = 0; ntb < 2; ntb++) {
        int gbase = w * 128 + ntb * 64;
        bf16x8 wf[8][4];
#pragma unroll
        for (int kt = 0; kt < 8; kt++)
#pragma unroll
          for (int nt = 0; nt < 4; nt++)
            wf[kt][nt] = *(const bf16x8*)(wsrc + (size_t)(gbase + nt * 16 + col) * 256 + kt * 32 + q * 8);
        f32x4 bias[4];
#pragma unroll
        for (int nt = 0; nt < 4; nt++)
#pragma unroll
          for (int rr = 0; rr < 4; rr++)
            bias[nt][rr] = btile[gbase + nt * 16 + q * 4 + rr];

#pragma unroll
        for (int st = 0; st < 8; st++) {
          bf16x8 xf[8];
#pragma unroll
          for (int kt = 0; kt < 8; kt++)
            xf[kt] = *(const bf16x8*)(xtile + (st * 16 + col) * 264 + kt * 32 + q * 8);
          f32x4 acc[4];
#pragma unroll
          for (int nt = 0; nt < 4; nt++) acc[nt] = bias[nt];
#pragma unroll
          for (int kt = 0; kt < 8; kt++)
#pragma unroll
            for (int nt = 0; nt < 4; nt++)
              acc[nt] = __builtin_amdgcn_mfma_f32_16x16x32_bf16(wf[kt][nt], xf[kt], acc[nt], 0, 0, 0);
          size_t off = (size_t)(k & 1) * 16777216 + (size_t)dir * 8388608
                     + (size_t)(ss * 8 + st) * 262144 + (size_t)(b0 + col) * 1024 + gbase;
#pragma unroll
          for (int nt = 0; nt < 4; nt++) {
            uint2 pk;
            pk.x = f2bf(acc[nt][0]) | ((unsigned int)f2bf(acc[nt][1]) << 16);
            pk.y = f2bf(acc[nt][2]) | ((unsigned int)f2bf(acc[nt][3]) << 16);
            *(uint2*)(gx + off + nt * 16 + q * 4) = pk;
          }
        }
      }
    }
    // tile done: barrier drains this block's gx stores, then device-scope release
    __syncthreads();
    if (tid == 0)
      __hip_atomic_fetch_add(&flags[k * 128 + ss * 32 + dir * 16 + sg], 1,
                             __ATOMIC_RELEASE, __HIP_MEMORY_SCOPE_AGENT);
  }
}

__device__ void lstm_role(
    const unsigned short* __restrict__ gx,
    const unsigned char* __restrict__ whh8,
    const unsigned char* __restrict__ wout8,
    const float* __restrict__ bout,
    const int* __restrict__ lens,
    unsigned short* __restrict__ emit_f, unsigned short* __restrict__ emit_b,
    int* flags, unsigned char (*hb4)[16 * 264])
{
  int bx = blockIdx.x;                 // 0..31
  int dir = bx & 1, grp = bx >> 1, b0 = grp * 16;   // grp = sg
  int tid = threadIdx.x, w = tid >> 6, lane = tid & 63, col = lane & 15, q = lane >> 4;
  int maxlen = lens[b0];               // sorted desc
  int bcl = b0 + col;                  // owned sentence (all 16 cols real)
  int mylen = lens[bcl];

  // ---- W_hh fp8 fragments fully into registers/AGPRs (64 x 8B), once ----
  const unsigned char* whb = whh8 + (size_t)dir * 262144;
  long wh[8][8];
#pragma unroll
  for (int kt = 0; kt < 8; kt++)
#pragma unroll
    for (int t = 0; t < 8; t++) {
      int row0 = (t & 3) * 256 + w * 32 + (t >> 2) * 16;
      wh[kt][t] = *(const long*)(whb + (size_t)(row0 + col) * 256 + kt * 32 + q * 8);
    }

  // ---- emission weights fp8: every wave holds tag-half (w&1)*16 ----
  long wo8[8];
  f32x4 bo4 = (f32x4){0.f, 0.f, 0.f, 0.f};
#pragma unroll
  for (int kt = 0; kt < 8; kt++)
    wo8[kt] = *(const long*)(wout8 + (size_t)((w & 1) * 16 + col) * 512 + dir * 256 + kt * 32 + q * 8);
  if (dir == 0) {
#pragma unroll
    for (int r = 0; r < 4; r++) bo4[r] = bout[(w & 1) * 16 + q * 4 + r];
  }
  unsigned short* ebase = dir ? emit_b : emit_f;

  // ---- persistent state (registers, whole sequence) ----
  float c8[8];
  long hf8[8];
#pragma unroll
  for (int i = 0; i < 8; i++) { c8[i] = 0.f; hf8[i] = 0; }

  for (int c = 0; c < 16; c++) {
    int s0 = c * 32;
    if (s0 < maxlen) {
      int cend = s0 + 32; if (cend > maxlen) cend = maxlen;
      const unsigned short* gbase = gx + (size_t)(c & 1) * 16777216 + (size_t)dir * 8388608
                                       + (size_t)bcl * 1024 + q * 4;
      for (int ss = 0; ss < 4; ss++) {
        int sp0 = s0 + ss * 8;
        if (sp0 >= maxlen) break;
        int spe = sp0 + 8; if (spe > cend) spe = cend;
        wait_ge(&flags[c * 128 + ss * 32 + dir * 16 + grp], 1);   // span produced

        uint2 gxr[8];
        {
          const unsigned short* gf = gbase + (size_t)(sp0 - s0) * 262144;
#pragma unroll
          for (int t = 0; t < 8; t++) {
            int row0 = (t & 3) * 256 + w * 32 + (t >> 2) * 16;
            gxr[t] = *(const uint2*)(gf + row0);
          }
        }

        for (int s = sp0; s < spe; s++) {
          f32x4 acc[8];
#pragma unroll
          for (int t = 0; t < 8; t++) {
            f32x4 a;
            a[0] = bf2f(gxr[t].x & 0xffffu); a[1] = bf2f(gxr[t].x >> 16);
            a[2] = bf2f(gxr[t].y & 0xffffu); a[3] = bf2f(gxr[t].y >> 16);
            acc[t] = a;
          }
          // prefetch gx for s+1 (within span only; span boundary reloads fresh)
          if (s + 1 < spe) {
            const unsigned short* gn = gbase + (size_t)(s + 1 - s0) * 262144;
#pragma unroll
            for (int t = 0; t < 8; t++) {
              int row0 = (t & 3) * 256 + w * 32 + (t >> 2) * 16;
              gxr[t] = *(const uint2*)(gn + row0);
            }
          }
          // h-part: fp8 MFMA, W resident
#pragma unroll
          for (int kt = 0; kt < 8; kt++) {
            long hv8 = hf8[kt];
#pragma unroll
            for (int t = 0; t < 8; t++)
              acc[t] = __builtin_amdgcn_mfma_f32_16x16x32_fp8_fp8(wh[kt][t], hv8, acc[t], 0, 0, 0);
          }
          // gates
          float hv[8];
#pragma unroll
          for (int a = 0; a < 2; a++)
#pragma unroll
            for (int r = 0; r < 4; r++) {
              float ig = acc[a * 4 + 0][r], fg = acc[a * 4 + 1][r];
              float gg = acc[a * 4 + 2][r], og = acc[a * 4 + 3][r];
              float cn = fsig(fg) * c8[a * 4 + r] + fsig(ig) * ftanh(gg);
              c8[a * 4 + r] = cn;
              hv[a * 4 + r] = fsig(og) * ftanh(cn);
            }
          // write fp8 h to 8-deep LDS history
          int par = s & 7;
#pragma unroll
          for (int a = 0; a < 2; a++) {
            int r8 = 0;
            r8 = __builtin_amdgcn_cvt_pk_fp8_f32(hv[a * 4 + 0], hv[a * 4 + 1], r8, false);
            r8 = __builtin_amdgcn_cvt_pk_fp8_f32(hv[a * 4 + 2], hv[a * 4 + 3], r8, true);
            *(unsigned int*)(&hb4[par][col * 264 + w * 32 + a * 16 + q * 4]) = (unsigned int)r8;
          }
          lds_barrier();   // lgkmcnt(0)+s_barrier only: no vmcnt drain in the chain
#pragma unroll
          for (int kt = 0; kt < 8; kt++)
            hf8[kt] = *(const long*)(&hb4[par][col * 264 + kt * 32 + q * 8]);

          // batched emission: one wave-pair per buffered step, every 4 steps
          if ((s & 3) == 3 || s == spe - 1) {
            int ebeg = s & ~3;
            int e = ebeg + (w >> 1);
            if (e <= s) {
              f32x4 ea = bo4;
#pragma unroll
              for (int kt = 0; kt < 8; kt++) {
                long hbv = *(const long*)(&hb4[e & 7][col * 264 + kt * 32 + q * 8]);
                ea = __builtin_amdgcn_mfma_f32_16x16x32_fp8_fp8(wo8[kt], hbv, ea, 0, 0, 0);
              }
              if (e < mylen) {
                int pos = dir ? (mylen - 1 - e) : e;
                uint2 pk;
                pk.x = f2bf(ea[0]) | ((unsigned int)f2bf(ea[1]) << 16);
                pk.y = f2bf(ea[2]) | ((unsigned int)f2bf(ea[3]) << 16);
                *(uint2*)(ebase + (((size_t)bcl * 512 + pos) * 32 + (w & 1) * 16 + q * 4)) = pk;
              }
            }
          }
        }
      }
    }
    // consumed chunk c (or never needed it): release parity for chunk c+2
    __syncthreads();
    if (tid == 0)
      __hip_atomic_fetch_add(&flags[2048 + c], 1, __ATOMIC_RELEASE, __HIP_MEMORY_SCOPE_AGENT);
  }
}

__global__ __launch_bounds__(512, 2) void fused_persist(
    const float* __restrict__ emb, const int* __restrict__ sent, const int* __restrict__ lens,
    const unsigned short* __restrict__ wih,
    const float* __restrict__ bih_f, const float* __restrict__ bhh_f,
    const float* __restrict__ bih_b, const float* __restrict__ bhh_b,
    unsigned short* __restrict__ gx,
    const unsigned char* __restrict__ whh8, const unsigned char* __restrict__ wout8,
    const float* __restrict__ bout,
    unsigned short* __restrict__ emit_f, unsigned short* __restrict__ emit_b,
    int* flags)
{
  __shared__ __align__(16) unsigned short xtile[128 * 264];
  __shared__ __align__(16) float btile[1024];
  __shared__ __align__(16) unsigned char hb4[8][16 * 264];

  if (blockIdx.x < 32) {
    lstm_role(gx, whh8, wout8, bout, lens, emit_f, emit_b, flags, hb4);
  } else {
    gemm_role(emb, sent, lens, wih, bih_f, bhh_f, bih_b, bhh_b, gx, flags, xtile, btile);
  }
}

// ---------------- K3: real-path score + CRF forward (bf16 emit in) ----------------
// 1 wave / sentence (256 blocks - latency-bound, keep max wave count).
__global__ __launch_bounds__(64) void crf_kernel(
    const unsigned short* __restrict__ emit_f,
    const unsigned short* __restrict__ emit_b,
    const float* __restrict__ trans, const int* __restrict__ tags,
    const int* __restrict__ lens, float* __restrict__ out) {
  const float LOG2E = 1.4426950408889634f, LN2 = 0.6931471805599453f;
  __shared__ __align__(16) float e_lds[512 * 32];   // 64 KB: log2e*(emit_f+emit_b)
  int b = blockIdx.x, lane = threadIdx.x;
  int len = lens[b];
  const int* tg = tags + b * 512;

  // ---- stage emit (coalesced bf16x8) -> LDS, pre-scaled by log2e ----
  size_t ebase = (size_t)b * 512 * 32;
  const unsigned short* pf = emit_f + ebase;
  const unsigned short* pb = emit_b + ebase;
  int ng = len * 4;                    // groups of 8 bf16
  for (int g = lane; g < ng; g += 64) {
    uint4v fv = *(const uint4v*)(pf + g * 8);
    uint4v bv = *(const uint4v*)(pb + g * 8);
    f32x4 w0, w1;
#pragma unroll
    for (int k = 0; k < 2; k++) {
      w0[2 * k]     = (bf2f(fv[k] & 0xffffu) + bf2f(bv[k] & 0xffffu)) * LOG2E;
      w0[2 * k + 1] = (bf2f(fv[k] >> 16)     + bf2f(bv[k] >> 16))     * LOG2E;
      w1[2 * k]     = (bf2f(fv[k + 2] & 0xffffu) + bf2f(bv[k + 2] & 0xffffu)) * LOG2E;
      w1[2 * k + 1] = (bf2f(fv[k + 2] >> 16)     + bf2f(bv[k + 2] >> 16))     * LOG2E;
    }
    *(f32x4*)(e_lds + g * 8) = w0;
    *(f32x4*)(e_lds + g * 8 + 4) = w1;
  }
  __syncthreads();

  // ---- real-path score (log2-scaled emit from LDS; trans in natural log) ----
  float rs2 = 0.f, rst = 0.f;
  for (int s = lane; s < len; s += 64) {
    int t1 = tg[s];
    rs2 += e_lds[s * 32 + t1];
    if (s > 0) rst += trans[tg[s - 1] * 32 + t1];
  }
  float rsc = LN2 * rs2 + rst;
#pragma unroll
  for (int m = 32; m; m >>= 1) rsc += __shfl_xor(rsc, m);

  // ---- CRF forward scan, log2 domain ----
  int j = lane & 31, half = lane >> 5, i0 = half * 16;
  float tr2[16];
  int pidx[16];
#pragma unroll
  for (int ii = 0; ii < 16; ii++) {
    tr2[ii] = trans[(i0 + ii) * 32 + j] * LOG2E;
    pidx[ii] = (i0 + ii) << 2;          // ds_bpermute byte index (hoisted)
  }
  const float* ep = e_lds + j;
  float B = ep[0];                       // log2-scaled alpha
  float e_nxt = ep[32];                  // len >= 256 always
  for (int s = 1; s < len; s++) {
    float e_cur = e_nxt;
    int sn = (s + 1 < len) ? (s + 1) : s;
    e_nxt = ep[sn * 32];                 // prefetch next step's emit (LDS)
    float v[16];
#pragma unroll
    for (int ii = 0; ii < 16; ii++)
      v[ii] = __builtin_bit_cast(float, __builtin_amdgcn_ds_bpermute(
                  pidx[ii], __builtin_bit_cast(int, B))) + tr2[ii];
    // depth-4 max tree
    float a8[8], a4[4], a2[2];
#pragma unroll
    for (int ii = 0; ii < 8; ii++) a8[ii] = fmaxf(v[ii], v[ii + 8]);
#pragma unroll
    for (int ii = 0; ii < 4; ii++) a4[ii] = fmaxf(a8[ii], a8[ii + 4]);
    a2[0] = fmaxf(a4[0], a4[2]); a2[1] = fmaxf(a4[1], a4[3]);
    float m1 = fmaxf(a2[0], a2[1]);
    float m2 = fmaxf(m1, __shfl_xor(m1, 32));
    // exp2 + depth-4 sum tree
    float x[16];
#pragma unroll
    for (int ii = 0; ii < 16; ii++) x[ii] = __builtin_amdgcn_exp2f(v[ii] - m2);
    float s8[8], s4[4], s2[2];
#pragma unroll
    for (int ii = 0; ii < 8; ii++) s8[ii] = x[ii] + x[ii + 8];
#pragma unroll
    for (int ii = 0; ii < 4; ii++) s4[ii] = s8[ii] + s8[ii + 4];
    s2[0] = s4[0] + s4[2]; s2[1] = s4[1] + s4[3];
    float sum = s2[0] + s2[1];
    sum += __shfl_xor(sum, 32);
    B = m2 + __builtin_amdgcn_logf(sum) + e_cur;   // v_log_f32 = log2
  }
  // log2-sum-exp2 over the 32 tags (halves hold identical B)
  float mz = B;
#pragma unroll
  for (int m = 16; m; m >>= 1) mz = fmaxf(mz, __shfl_xor(mz, m));
  float sz = __builtin_amdgcn_exp2f(B - mz);
#pragma unroll
  for (int m = 16; m; m >>= 1) sz += __shfl_xor(sz, m);
  float logz = LN2 * (mz + __builtin_amdgcn_logf(sz));
  if (lane == 0) out[b] = logz - rsc;
}

// ---------------- launch ----------------
extern "C" void kernel_launch(void* const* d_in, const int* in_sizes, int n_in,
                              void* d_out, int out_size, void* d_ws, size_t ws_size,
                              hipStream_t stream) {
  const float* emb   = (const float*)d_in[0];
  const float* Wih_f = (const float*)d_in[1];
  const float* Whh_f = (const float*)d_in[2];
  const float* bih_f = (const float*)d_in[3];
  const float* bhh_f = (const float*)d_in[4];
  const float* Wih_b = (const float*)d_in[5];
  const float* Whh_b = (const float*)d_in[6];
  const float* bih_b = (const float*)d_in[7];
  const float* bhh_b = (const float*)d_in[8];
  const float* Wout  = (const float*)d_in[9];
  const float* bout  = (const float*)d_in[10];
  const float* trans = (const float*)d_in[11];
  const int* sent = (const int*)d_in[12];
  const int* tags = (const int*)d_in[13];
  const int* lens = (const int*)d_in[14];
  float* out = (float*)d_out;

  // workspace layout (bytes), total 87,048,192
  char* ws = (char*)d_ws;
  if (ws_size < 87048192ull) return;
  unsigned short* gx      = (unsigned short*)(ws);                // 67,108,864 (2 parity x 32s)
  unsigned short* emit_f  = (unsigned short*)(ws + 67108864);     //  8,388,608
  unsigned short* emit_b  = (unsigned short*)(ws + 75497472);     //  8,388,608
  unsigned short* wih_bf  = (unsigned short*)(ws + 83886080);     //  1,048,576
  unsigned char*  whh8    = (unsigned char*)(ws + 84934656);      //    524,288
  unsigned char*  wout8   = (unsigned char*)(ws + 85458944);      //     16,384
  int*            flags   = (int*)(ws + 85475328);                //  8,320 (ready+done)

  cvt_weights<<<1040, 256, 0, stream>>>(Wih_f, Wih_b, Whh_f, Whh_b, Wout,
                                        wih_bf, whh8, wout8, flags);
  fused_persist<<<256, 512, 0, stream>>>(
      emb, sent, lens, wih_bf, bih_f, bhh_f, bih_b, bhh_b, gx,
      whh8, wout8, bout, emit_f, emit_b, flags);
  crf_kernel<<<256, 64, 0, stream>>>(emit_f, emit_b, trans, tags, lens, out);
}

// Round 8
// 1461.680 us; speedup vs baseline: 1.1800x; 1.0442x over previous
//
#include <hip/hip_runtime.h>
#include <hip/hip_bf16.h>

// BiLSTM-CRF forward, MI355X gfx950.
// B=256, S=512, E=256, H=256, G=4H=1024, T=32, PAD=49999.
//
// Round-15 = round-14 structure, lstm h-MFMAs switched to MX-scaled fp8 K=128.
//   v_mfma_scale_f32_16x16x128_f8f6f4 (scales=1.0) runs ~2.25x the non-scaled
//   fp8 rate -> h-part per wave-step: 16 MFMAs (was 64), matrix-pipe issue
//   ~1104 cy/SIMD-step (was ~2480). Same W bytes (128 regs), same math
//   (fp8 e4m3 products, fp32 accum). Emission MFMAs likewise K=128.
//   hbuf row stride 264 -> 272 for 16B-aligned b128 fragment reads.
//   gemm role (round-14: 1024g x 16b x 8s tile, single emb gather) unchanged.
//   crf: 1 sentence/block, LDS-staged log2-domain scan (proven 167us).

typedef __bf16 bf16x8 __attribute__((ext_vector_type(8)));
typedef float f32x4 __attribute__((ext_vector_type(4)));
typedef unsigned int uint4v __attribute__((ext_vector_type(4)));
typedef int i32x8 __attribute__((ext_vector_type(8)));

__device__ __forceinline__ unsigned short f2bf(float f) {
  union { float f; unsigned int u; } v; v.f = f;
  unsigned int r = v.u + 0x7fffu + ((v.u >> 16) & 1u);   // RNE
  return (unsigned short)(r >> 16);
}
__device__ __forceinline__ float bf2f(unsigned int lo16) {
  union { unsigned int u; float f; } v; v.u = lo16 << 16;
  return v.f;
}
__device__ __forceinline__ float fsig(float x) {
  float e = __builtin_amdgcn_exp2f(-1.4426950408889634f * x);
  return __builtin_amdgcn_rcpf(1.0f + e);
}
__device__ __forceinline__ float ftanh(float x) {
  float e = __builtin_amdgcn_exp2f(2.8853900817779268f * x);
  return 1.0f - 2.0f * __builtin_amdgcn_rcpf(e + 1.0f);
}

// 32-byte load as two 16B vectors (safe at 16B alignment for LDS rows).
__device__ __forceinline__ i32x8 ld32(const unsigned char* p) {
  uint4v lo = *(const uint4v*)(p);
  uint4v hi = *(const uint4v*)(p + 16);
  i32x8 r;
  r[0] = (int)lo[0]; r[1] = (int)lo[1]; r[2] = (int)lo[2]; r[3] = (int)lo[3];
  r[4] = (int)hi[0]; r[5] = (int)hi[1]; r[6] = (int)hi[2]; r[7] = (int)hi[3];
  return r;
}

__device__ __forceinline__ void wait_ge(int* p, int target) {
  if (threadIdx.x == 0) {
    while (__hip_atomic_load(p, __ATOMIC_RELAXED, __HIP_MEMORY_SCOPE_AGENT) < target)
      __builtin_amdgcn_s_sleep(2);
    (void)__hip_atomic_load(p, __ATOMIC_ACQUIRE, __HIP_MEMORY_SCOPE_AGENT);
  }
  __syncthreads();
}

// LDS-only barrier: no vmcnt(0) drain (keeps emission stores / gx prefetch
// loads in flight across the per-step h exchange).
__device__ __forceinline__ void lds_barrier() {
  asm volatile("s_waitcnt lgkmcnt(0)\n\ts_barrier" ::: "memory");
}

// ---------------- K0: weight conversion + flag reset ----------------
__global__ void cvt_weights(const float* __restrict__ wih_f, const float* __restrict__ wih_b,
                            const float* __restrict__ whh_f, const float* __restrict__ whh_b,
                            const float* __restrict__ wo,
                            unsigned short* __restrict__ wih,    // bf16 [2][1024][256]
                            unsigned char* __restrict__ whh8,    // fp8  [2][1024][256]
                            unsigned char* __restrict__ wout8,   // fp8  [32][512]
                            int* __restrict__ flags) {           // ready[2048] + done[16]
  if (blockIdx.x == 0) {
    for (int f = threadIdx.x; f < 2080; f += 256) flags[f] = 0;
  }
  int t = blockIdx.x * 256 + threadIdx.x;
  int i = t * 4;
  if (i < 524288) {
    const float* src = (i < 262144) ? wih_f : wih_b;
    f32x4 v = *(const f32x4*)(src + (i & 262143));
    uint2 p;
    p.x = f2bf(v[0]) | ((unsigned int)f2bf(v[1]) << 16);
    p.y = f2bf(v[2]) | ((unsigned int)f2bf(v[3]) << 16);
    *(uint2*)(wih + i) = p;
  } else if (i < 1048576) {
    int k = i - 524288;
    const float* src = (k < 262144) ? whh_f : whh_b;
    f32x4 v = *(const f32x4*)(src + (k & 262143));
    int r = 0;
    r = __builtin_amdgcn_cvt_pk_fp8_f32(v[0], v[1], r, false);
    r = __builtin_amdgcn_cvt_pk_fp8_f32(v[2], v[3], r, true);
    *(unsigned int*)(whh8 + k) = (unsigned int)r;
  } else if (i < 1064960) {
    int k = i - 1048576;
    f32x4 v = *(const f32x4*)(wo + k);
    int r = 0;
    r = __builtin_amdgcn_cvt_pk_fp8_f32(v[0], v[1], r, false);
    r = __builtin_amdgcn_cvt_pk_fp8_f32(v[2], v[3], r, true);
    *(unsigned int*)(wout8 + k) = (unsigned int)r;
  }
}

// ---------------- persistent roles ----------------
// gx layout: [parity][dir][32 s][256 b][1024 g] bf16
//   parity stride 16,777,216 elems; dir 8,388,608; s 262,144.
// flags: ready[k*128 + ss*32 + dir*16 + sg] (target 1, single producer),
//        done[2048 + k] (target 32 = lstm blocks).

__device__ void gemm_role(
    const float* __restrict__ emb, const int* __restrict__ sent, const int* __restrict__ lens,
    const unsigned short* __restrict__ wih,
    const float* __restrict__ bih_f, const float* __restrict__ bhh_f,
    const float* __restrict__ bih_b, const float* __restrict__ bhh_b,
    unsigned short* __restrict__ gx, int* flags,
    unsigned short* xtile,      // [128][264] bf16 (row = st*16 + si)
    float* btile)               // [1024]
{
  int gb = blockIdx.x - 32;   // 0..223
  int tid = threadIdx.x, w = tid >> 6, lane = tid & 63, col = lane & 15, q = lane >> 4;
  int prev_chunk = -1;

  for (int idx = gb; idx < 2048; idx += 224) {
    int k = idx >> 7, t = idx & 127;
    int ss = t >> 5, dir = (t >> 4) & 1, sg = t & 15;
    if (k != prev_chunk) {
      prev_chunk = k;
      if (k >= 2) wait_ge(&flags[2048 + k - 2], 32);   // parity reuse backpressure
    }
    int b0 = sg * 16;
    int sbase = k * 32 + ss * 8;

    if (sbase < lens[b0]) {   // sorted desc: lens[b0] = group max
      // ---- stage x: 128 emb rows (16 sent x 8 steps) -> bf16 LDS, once ----
      {
        int r = tid >> 2, t4 = tid & 3;       // 4 threads per row, 64 f32 each
        int st = r >> 4, si = r & 15;
        int bidx = b0 + si;
        int len = lens[bidx];
        int s = sbase + st;
        int s_eff = dir ? ((s < len) ? (len - 1 - s) : s) : s;
        int token = sent[bidx * 512 + s_eff];
        const float* ep = emb + (size_t)token * 256 + t4 * 64;
        unsigned short* xd = xtile + r * 264 + t4 * 64;
#pragma unroll
        for (int u = 0; u < 4; u++) {
          f32x4 a0 = *(const f32x4*)(ep + u * 16);
          f32x4 a1 = *(const f32x4*)(ep + u * 16 + 4);
          f32x4 a2 = *(const f32x4*)(ep + u * 16 + 8);
          f32x4 a3 = *(const f32x4*)(ep + u * 16 + 12);
          uint4v p0, p1;
          p0[0] = f2bf(a0[0]) | ((unsigned int)f2bf(a0[1]) << 16);
          p0[1] = f2bf(a0[2]) | ((unsigned int)f2bf(a0[3]) << 16);
          p0[2] = f2bf(a1[0]) | ((unsigned int)f2bf(a1[1]) << 16);
          p0[3] = f2bf(a1[2]) | ((unsigned int)f2bf(a1[3]) << 16);
          p1[0] = f2bf(a2[0]) | ((unsigned int)f2bf(a2[1]) << 16);
          p1[1] = f2bf(a2[2]) | ((unsigned int)f2bf(a2[3]) << 16);
          p1[2] = f2bf(a3[0]) | ((unsigned int)f2bf(a3[1]) << 16);
          p1[3] = f2bf(a3[2]) | ((unsigned int)f2bf(a3[3]) << 16);
          *(uint4v*)(xd + u * 16) = p0;
          *(uint4v*)(xd + u * 16 + 8) = p1;
        }
        const float* bi = dir ? bih_b : bih_f;
        const float* bh = dir ? bhh_b : bhh_f;
        btile[tid] = bi[tid] + bh[tid];
        btile[tid + 512] = bi[tid + 512] + bh[tid + 512];
      }
      __syncthreads();

      // ---- compute: wave w -> gates [w*128, w*128+128), 2 blocks of 64 ----
      const unsigned short* wsrc = wih + (size_t)dir * 262144;
#pragma unroll
      for (int ntb = 0; ntb < 2; ntb++) {
        int gbase = w * 128 + ntb * 64;
        bf16x8 wf[8][4];
#pragma unroll
        for (int kt = 0; kt < 8; kt++)
#pragma unroll
          for (int nt = 0; nt < 4; nt++)
            wf[kt][nt] = *(const bf16x8*)(wsrc + (size_t)(gbase + nt * 16 + col) * 256 + kt * 32 + q * 8);
        f32x4 bias[4];
#pragma unroll
        for (int nt = 0; nt < 4; nt++)
#pragma unroll
          for (int rr = 0; rr < 4; rr++)
            bias[nt][rr] = btile[gbase + nt * 16 + q * 4 + rr];

#pragma unroll
        for (int st = 0; st < 8; st++) {
          bf16x8 xf[8];
#pragma unroll
          for (int kt = 0; kt < 8; kt++)
            xf[kt] = *(const bf16x8*)(xtile + (st * 16 + col) * 264 + kt * 32 + q * 8);
          f32x4 acc[4];
#pragma unroll
          for (int nt = 0; nt < 4; nt++) acc[nt] = bias[nt];
#pragma unroll
          for (int kt = 0; kt < 8; kt++)
#pragma unroll
            for (int nt = 0; nt < 4; nt++)
              acc[nt] = __builtin_amdgcn_mfma_f32_16x16x32_bf16(wf[kt][nt], xf[kt], acc[nt], 0, 0, 0);
          size_t off = (size_t)(k & 1) * 16777216 + (size_t)dir * 8388608
                     + (size_t)(ss * 8 + st) * 262144 + (size_t)(b0 + col) * 1024 + gbase;
#pragma unroll
          for (int nt = 0; nt < 4; nt++) {
            uint2 pk;
            pk.x = f2bf(acc[nt][0]) | ((unsigned int)f2bf(acc[nt][1]) << 16);
            pk.y = f2bf(acc[nt][2]) | ((unsigned int)f2bf(acc[nt][3]) << 16);
            *(uint2*)(gx + off + nt * 16 + q * 4) = pk;
          }
        }
      }
    }
    // tile done: barrier drains this block's gx stores, then device-scope release
    __syncthreads();
    if (tid == 0)
      __hip_atomic_fetch_add(&flags[k * 128 + ss * 32 + dir * 16 + sg], 1,
                             __ATOMIC_RELEASE, __HIP_MEMORY_SCOPE_AGENT);
  }
}

__device__ void lstm_role(
    const unsigned short* __restrict__ gx,
    const unsigned char* __restrict__ whh8,
    const unsigned char* __restrict__ wout8,
    const float* __restrict__ bout,
    const int* __restrict__ lens,
    unsigned short* __restrict__ emit_f, unsigned short* __restrict__ emit_b,
    int* flags, unsigned char (*hb4)[16 * 272])
{
  int bx = blockIdx.x;                 // 0..31
  int dir = bx & 1, grp = bx >> 1, b0 = grp * 16;   // grp = sg
  int tid = threadIdx.x, w = tid >> 6, lane = tid & 63, col = lane & 15, q = lane >> 4;
  int maxlen = lens[b0];               // sorted desc
  int bcl = b0 + col;                  // owned sentence (all 16 cols real)
  int mylen = lens[bcl];

  // ---- W_hh fp8 fragments for K=128 scaled MFMA: 8 row-tiles x 2 k-halves ----
  const unsigned char* whb = whh8 + (size_t)dir * 262144;
  i32x8 wh[8][2];
#pragma unroll
  for (int t = 0; t < 8; t++) {
    int row0 = (t & 3) * 256 + w * 32 + (t >> 2) * 16;
#pragma unroll
    for (int kh = 0; kh < 2; kh++)
      wh[t][kh] = ld32(whb + (size_t)(row0 + col) * 256 + kh * 128 + q * 32);
  }

  // ---- emission weights fp8 K=128: every wave holds tag-half (w&1)*16 ----
  i32x8 wo[2];
  f32x4 bo4 = (f32x4){0.f, 0.f, 0.f, 0.f};
#pragma unroll
  for (int kh = 0; kh < 2; kh++)
    wo[kh] = ld32(wout8 + (size_t)((w & 1) * 16 + col) * 512 + dir * 256 + kh * 128 + q * 32);
  if (dir == 0) {
#pragma unroll
    for (int r = 0; r < 4; r++) bo4[r] = bout[(w & 1) * 16 + q * 4 + r];
  }
  unsigned short* ebase = dir ? emit_b : emit_f;

  // ---- persistent state (registers, whole sequence) ----
  float c8[8];
  i32x8 hf[2];
#pragma unroll
  for (int i = 0; i < 8; i++) c8[i] = 0.f;
#pragma unroll
  for (int kh = 0; kh < 2; kh++)
#pragma unroll
    for (int i = 0; i < 8; i++) hf[kh][i] = 0;

  for (int c = 0; c < 16; c++) {
    int s0 = c * 32;
    if (s0 < maxlen) {
      int cend = s0 + 32; if (cend > maxlen) cend = maxlen;
      const unsigned short* gbase = gx + (size_t)(c & 1) * 16777216 + (size_t)dir * 8388608
                                       + (size_t)bcl * 1024 + q * 4;
      for (int ss = 0; ss < 4; ss++) {
        int sp0 = s0 + ss * 8;
        if (sp0 >= maxlen) break;
        int spe = sp0 + 8; if (spe > cend) spe = cend;
        wait_ge(&flags[c * 128 + ss * 32 + dir * 16 + grp], 1);   // span produced

        uint2 gxr[8];
        {
          const unsigned short* gf = gbase + (size_t)(sp0 - s0) * 262144;
#pragma unroll
          for (int t = 0; t < 8; t++) {
            int row0 = (t & 3) * 256 + w * 32 + (t >> 2) * 16;
            gxr[t] = *(const uint2*)(gf + row0);
          }
        }

        for (int s = sp0; s < spe; s++) {
          f32x4 acc[8];
#pragma unroll
          for (int t = 0; t < 8; t++) {
            f32x4 a;
            a[0] = bf2f(gxr[t].x & 0xffffu); a[1] = bf2f(gxr[t].x >> 16);
            a[2] = bf2f(gxr[t].y & 0xffffu); a[3] = bf2f(gxr[t].y >> 16);
            acc[t] = a;
          }
          // prefetch gx for s+1 (within span only; span boundary reloads fresh)
          if (s + 1 < spe) {
            const unsigned short* gn = gbase + (size_t)(s + 1 - s0) * 262144;
#pragma unroll
            for (int t = 0; t < 8; t++) {
              int row0 = (t & 3) * 256 + w * 32 + (t >> 2) * 16;
              gxr[t] = *(const uint2*)(gn + row0);
            }
          }
          // h-part: MX-scaled fp8 MFMA K=128 (scales = 1.0), W resident
#pragma unroll
          for (int kh = 0; kh < 2; kh++) {
            i32x8 hv8 = hf[kh];
#pragma unroll
            for (int t = 0; t < 8; t++)
              acc[t] = __builtin_amdgcn_mfma_scale_f32_16x16x128_f8f6f4(
                  wh[t][kh], hv8, acc[t], 0, 0, 0, 127, 0, 127);
          }
          // gates
          float hv[8];
#pragma unroll
          for (int a = 0; a < 2; a++)
#pragma unroll
            for (int r = 0; r < 4; r++) {
              float ig = acc[a * 4 + 0][r], fg = acc[a * 4 + 1][r];
              float gg = acc[a * 4 + 2][r], og = acc[a * 4 + 3][r];
              float cn = fsig(fg) * c8[a * 4 + r] + fsig(ig) * ftanh(gg);
              c8[a * 4 + r] = cn;
              hv[a * 4 + r] = fsig(og) * ftanh(cn);
            }
          // write fp8 h to 8-deep LDS history
          int par = s & 7;
#pragma unroll
          for (int a = 0; a < 2; a++) {
            int r8 = 0;
            r8 = __builtin_amdgcn_cvt_pk_fp8_f32(hv[a * 4 + 0], hv[a * 4 + 1], r8, false);
            r8 = __builtin_amdgcn_cvt_pk_fp8_f32(hv[a * 4 + 2], hv[a * 4 + 3], r8, true);
            *(unsigned int*)(&hb4[par][col * 272 + w * 32 + a * 16 + q * 4]) = (unsigned int)r8;
          }
          lds_barrier();   // lgkmcnt(0)+s_barrier only: no vmcnt drain in the chain
#pragma unroll
          for (int kh = 0; kh < 2; kh++)
            hf[kh] = ld32(&hb4[par][col * 272 + kh * 128 + q * 32]);

          // batched emission: one wave-pair per buffered step, every 4 steps
          if ((s & 3) == 3 || s == spe - 1) {
            int ebeg = s & ~3;
            int e = ebeg + (w >> 1);
            if (e <= s) {
              f32x4 ea = bo4;
#pragma unroll
              for (int kh = 0; kh < 2; kh++) {
                i32x8 hbv = ld32(&hb4[e & 7][col * 272 + kh * 128 + q * 32]);
                ea = __builtin_amdgcn_mfma_scale_f32_16x16x128_f8f6f4(
                    wo[kh], hbv, ea, 0, 0, 0, 127, 0, 127);
              }
              if (e < mylen) {
                int pos = dir ? (mylen - 1 - e) : e;
                uint2 pk;
                pk.x = f2bf(ea[0]) | ((unsigned int)f2bf(ea[1]) << 16);
                pk.y = f2bf(ea[2]) | ((unsigned int)f2bf(ea[3]) << 16);
                *(uint2*)(ebase + (((size_t)bcl * 512 + pos) * 32 + (w & 1) * 16 + q * 4)) = pk;
              }
            }
          }
        }
      }
    }
    // consumed chunk c (or never needed it): release parity for chunk c+2
    __syncthreads();
    if (tid == 0)
      __hip_atomic_fetch_add(&flags[2048 + c], 1, __ATOMIC_RELEASE, __HIP_MEMORY_SCOPE_AGENT);
  }
}

__global__ __launch_bounds__(512, 2) void fused_persist(
    const float* __restrict__ emb, const int* __restrict__ sent, const int* __restrict__ lens,
    const unsigned short* __restrict__ wih,
    const float* __restrict__ bih_f, const float* __restrict__ bhh_f,
    const float* __restrict__ bih_b, const float* __restrict__ bhh_b,
    unsigned short* __restrict__ gx,
    const unsigned char* __restrict__ whh8, const unsigned char* __restrict__ wout8,
    const float* __restrict__ bout,
    unsigned short* __restrict__ emit_f, unsigned short* __restrict__ emit_b,
    int* flags)
{
  __shared__ __align__(16) unsigned short xtile[128 * 264];
  __shared__ __align__(16) float btile[1024];
  __shared__ __align__(16) unsigned char hb4[8][16 * 272];

  if (blockIdx.x < 32) {
    lstm_role(gx, whh8, wout8, bout, lens, emit_f, emit_b, flags, hb4);
  } else {
    gemm_role(emb, sent, lens, wih, bih_f, bhh_f, bih_b, bhh_b, gx, flags, xtile, btile);
  }
}

// ---------------- K3: real-path score + CRF forward (bf16 emit in) ----------------
// 1 wave / sentence (256 blocks - latency-bound, keep max wave count).
__global__ __launch_bounds__(64) void crf_kernel(
    const unsigned short* __restrict__ emit_f,
    const unsigned short* __restrict__ emit_b,
    const float* __restrict__ trans, const int* __restrict__ tags,
    const int* __restrict__ lens, float* __restrict__ out) {
  const float LOG2E = 1.4426950408889634f, LN2 = 0.6931471805599453f;
  __shared__ __align__(16) float e_lds[512 * 32];   // 64 KB: log2e*(emit_f+emit_b)
  int b = blockIdx.x, lane = threadIdx.x;
  int len = lens[b];
  const int* tg = tags + b * 512;

  // ---- stage emit (coalesced bf16x8) -> LDS, pre-scaled by log2e ----
  size_t ebase = (size_t)b * 512 * 32;
  const unsigned short* pf = emit_f + ebase;
  const unsigned short* pb = emit_b + ebase;
  int ng = len * 4;                    // groups of 8 bf16
  for (int g = lane; g < ng; g += 64) {
    uint4v fv = *(const uint4v*)(pf + g * 8);
    uint4v bv = *(const uint4v*)(pb + g * 8);
    f32x4 w0, w1;
#pragma unroll
    for (int k = 0; k < 2; k++) {
      w0[2 * k]     = (bf2f(fv[k] & 0xffffu) + bf2f(bv[k] & 0xffffu)) * LOG2E;
      w0[2 * k + 1] = (bf2f(fv[k] >> 16)     + bf2f(bv[k] >> 16))     * LOG2E;
      w1[2 * k]     = (bf2f(fv[k + 2] & 0xffffu) + bf2f(bv[k + 2] & 0xffffu)) * LOG2E;
      w1[2 * k + 1] = (bf2f(fv[k + 2] >> 16)     + bf2f(bv[k + 2] >> 16))     * LOG2E;
    }
    *(f32x4*)(e_lds + g * 8) = w0;
    *(f32x4*)(e_lds + g * 8 + 4) = w1;
  }
  __syncthreads();

  // ---- real-path score (log2-scaled emit from LDS; trans in natural log) ----
  float rs2 = 0.f, rst = 0.f;
  for (int s = lane; s < len; s += 64) {
    int t1 = tg[s];
    rs2 += e_lds[s * 32 + t1];
    if (s > 0) rst += trans[tg[s - 1] * 32 + t1];
  }
  float rsc = LN2 * rs2 + rst;
#pragma unroll
  for (int m = 32; m; m >>= 1) rsc += __shfl_xor(rsc, m);

  // ---- CRF forward scan, log2 domain ----
  int j = lane & 31, half = lane >> 5, i0 = half * 16;
  float tr2[16];
  int pidx[16];
#pragma unroll
  for (int ii = 0; ii < 16; ii++) {
    tr2[ii] = trans[(i0 + ii) * 32 + j] * LOG2E;
    pidx[ii] = (i0 + ii) << 2;          // ds_bpermute byte index (hoisted)
  }
  const float* ep = e_lds + j;
  float B = ep[0];                       // log2-scaled alpha
  float e_nxt = ep[32];                  // len >= 256 always
  for (int s = 1; s < len; s++) {
    float e_cur = e_nxt;
    int sn = (s + 1 < len) ? (s + 1) : s;
    e_nxt = ep[sn * 32];                 // prefetch next step's emit (LDS)
    float v[16];
#pragma unroll
    for (int ii = 0; ii < 16; ii++)
      v[ii] = __builtin_bit_cast(float, __builtin_amdgcn_ds_bpermute(
                  pidx[ii], __builtin_bit_cast(int, B))) + tr2[ii];
    // depth-4 max tree
    float a8[8], a4[4], a2[2];
#pragma unroll
    for (int ii = 0; ii < 8; ii++) a8[ii] = fmaxf(v[ii], v[ii + 8]);
#pragma unroll
    for (int ii = 0; ii < 4; ii++) a4[ii] = fmaxf(a8[ii], a8[ii + 4]);
    a2[0] = fmaxf(a4[0], a4[2]); a2[1] = fmaxf(a4[1], a4[3]);
    float m1 = fmaxf(a2[0], a2[1]);
    float m2 = fmaxf(m1, __shfl_xor(m1, 32));
    // exp2 + depth-4 sum tree
    float x[16];
#pragma unroll
    for (int ii = 0; ii < 16; ii++) x[ii] = __builtin_amdgcn_exp2f(v[ii] - m2);
    float s8[8], s4[4], s2[2];
#pragma unroll
    for (int ii = 0; ii < 8; ii++) s8[ii] = x[ii] + x[ii + 8];
#pragma unroll
    for (int ii = 0; ii < 4; ii++) s4[ii] = s8[ii] + s8[ii + 4];
    s2[0] = s4[0] + s4[2]; s2[1] = s4[1] + s4[3];
    float sum = s2[0] + s2[1];
    sum += __shfl_xor(sum, 32);
    B = m2 + __builtin_amdgcn_logf(sum) + e_cur;   // v_log_f32 = log2
  }
  // log2-sum-exp2 over the 32 tags (halves hold identical B)
  float mz = B;
#pragma unroll
  for (int m = 16; m; m >>= 1) mz = fmaxf(mz, __shfl_xor(mz, m));
  float sz = __builtin_amdgcn_exp2f(B - mz);
#pragma unroll
  for (int m = 16; m; m >>= 1) sz += __shfl_xor(sz, m);
  float logz = LN2 * (mz + __builtin_amdgcn_logf(sz));
  if (lane == 0) out[b] = logz - rsc;
}

// ---------------- launch ----------------
extern "C" void kernel_launch(void* const* d_in, const int* in_sizes, int n_in,
                              void* d_out, int out_size, void* d_ws, size_t ws_size,
                              hipStream_t stream) {
  const float* emb   = (const float*)d_in[0];
  const float* Wih_f = (const float*)d_in[1];
  const float* Whh_f = (const float*)d_in[2];
  const float* bih_f = (const float*)d_in[3];
  const float* bhh_f = (const float*)d_in[4];
  const float* Wih_b = (const float*)d_in[5];
  const float* Whh_b = (const float*)d_in[6];
  const float* bih_b = (const float*)d_in[7];
  const float* bhh_b = (const float*)d_in[8];
  const float* Wout  = (const float*)d_in[9];
  const float* bout  = (const float*)d_in[10];
  const float* trans = (const float*)d_in[11];
  const int* sent = (const int*)d_in[12];
  const int* tags = (const int*)d_in[13];
  const int* lens = (const int*)d_in[14];
  float* out = (float*)d_out;

  // workspace layout (bytes), total 87,048,192
  char* ws = (char*)d_ws;
  if (ws_size < 87048192ull) return;
  unsigned short* gx      = (unsigned short*)(ws);                // 67,108,864 (2 parity x 32s)
  unsigned short* emit_f  = (unsigned short*)(ws + 67108864);     //  8,388,608
  unsigned short* emit_b  = (unsigned short*)(ws + 75497472);     //  8,388,608
  unsigned short* wih_bf  = (unsigned short*)(ws + 83886080);     //  1,048,576
  unsigned char*  whh8    = (unsigned char*)(ws + 84934656);      //    524,288
  unsigned char*  wout8   = (unsigned char*)(ws + 85458944);      //     16,384
  int*            flags   = (int*)(ws + 85475328);                //  8,320 (ready+done)

  cvt_weights<<<1040, 256, 0, stream>>>(Wih_f, Wih_b, Whh_f, Whh_b, Wout,
                                        wih_bf, whh8, wout8, flags);
  fused_persist<<<256, 512, 0, stream>>>(
      emb, sent, lens, wih_bf, bih_f, bhh_f, bih_b, bhh_b, gx,
      whh8, wout8, bout, emit_f, emit_b, flags);
  crf_kernel<<<256, 64, 0, stream>>>(emit_f, emit_b, trans, tags, lens, out);
}

// Round 9
// 1446.858 us; speedup vs baseline: 1.1921x; 1.0102x over previous
//
#include <hip/hip_runtime.h>
#include <hip/hip_bf16.h>

// BiLSTM-CRF forward, MI355X gfx950.
// B=256, S=512, E=256, H=256, G=4H=1024, T=32, PAD=49999.
//
// Round-16 = round-15 + amdgpu_waves_per_eu(2,2) on fused_persist.
//   DIAGNOSIS: VGPR_Count=128 all rounds, but lstm needs ~250 regs to keep
//   W_hh fragments resident. At 128 the compiler rematerializes the W loads
//   every step -> 256KB/block-step re-streamed from L2 (~1.9us/step) = the
//   invariant ~2.4us step cost. Forcing exactly 2 waves/EU raises the
//   register budget to 256/wave (occupancy unchanged: 8 waves, 1 block/CU),
//   letting W_hh + W_out + state live in registers across all 512 steps.
//   Everything else byte-identical to round-15.

typedef __bf16 bf16x8 __attribute__((ext_vector_type(8)));
typedef float f32x4 __attribute__((ext_vector_type(4)));
typedef unsigned int uint4v __attribute__((ext_vector_type(4)));
typedef int i32x8 __attribute__((ext_vector_type(8)));

__device__ __forceinline__ unsigned short f2bf(float f) {
  union { float f; unsigned int u; } v; v.f = f;
  unsigned int r = v.u + 0x7fffu + ((v.u >> 16) & 1u);   // RNE
  return (unsigned short)(r >> 16);
}
__device__ __forceinline__ float bf2f(unsigned int lo16) {
  union { unsigned int u; float f; } v; v.u = lo16 << 16;
  return v.f;
}
__device__ __forceinline__ float fsig(float x) {
  float e = __builtin_amdgcn_exp2f(-1.4426950408889634f * x);
  return __builtin_amdgcn_rcpf(1.0f + e);
}
__device__ __forceinline__ float ftanh(float x) {
  float e = __builtin_amdgcn_exp2f(2.8853900817779268f * x);
  return 1.0f - 2.0f * __builtin_amdgcn_rcpf(e + 1.0f);
}

// 32-byte load as two 16B vectors (safe at 16B alignment for LDS rows).
__device__ __forceinline__ i32x8 ld32(const unsigned char* p) {
  uint4v lo = *(const uint4v*)(p);
  uint4v hi = *(const uint4v*)(p + 16);
  i32x8 r;
  r[0] = (int)lo[0]; r[1] = (int)lo[1]; r[2] = (int)lo[2]; r[3] = (int)lo[3];
  r[4] = (int)hi[0]; r[5] = (int)hi[1]; r[6] = (int)hi[2]; r[7] = (int)hi[3];
  return r;
}

__device__ __forceinline__ void wait_ge(int* p, int target) {
  if (threadIdx.x == 0) {
    while (__hip_atomic_load(p, __ATOMIC_RELAXED, __HIP_MEMORY_SCOPE_AGENT) < target)
      __builtin_amdgcn_s_sleep(2);
    (void)__hip_atomic_load(p, __ATOMIC_ACQUIRE, __HIP_MEMORY_SCOPE_AGENT);
  }
  __syncthreads();
}

// LDS-only barrier: no vmcnt(0) drain (keeps emission stores / gx prefetch
// loads in flight across the per-step h exchange).
__device__ __forceinline__ void lds_barrier() {
  asm volatile("s_waitcnt lgkmcnt(0)\n\ts_barrier" ::: "memory");
}

// ---------------- K0: weight conversion + flag reset ----------------
__global__ void cvt_weights(const float* __restrict__ wih_f, const float* __restrict__ wih_b,
                            const float* __restrict__ whh_f, const float* __restrict__ whh_b,
                            const float* __restrict__ wo,
                            unsigned short* __restrict__ wih,    // bf16 [2][1024][256]
                            unsigned char* __restrict__ whh8,    // fp8  [2][1024][256]
                            unsigned char* __restrict__ wout8,   // fp8  [32][512]
                            int* __restrict__ flags) {           // ready[2048] + done[16]
  if (blockIdx.x == 0) {
    for (int f = threadIdx.x; f < 2080; f += 256) flags[f] = 0;
  }
  int t = blockIdx.x * 256 + threadIdx.x;
  int i = t * 4;
  if (i < 524288) {
    const float* src = (i < 262144) ? wih_f : wih_b;
    f32x4 v = *(const f32x4*)(src + (i & 262143));
    uint2 p;
    p.x = f2bf(v[0]) | ((unsigned int)f2bf(v[1]) << 16);
    p.y = f2bf(v[2]) | ((unsigned int)f2bf(v[3]) << 16);
    *(uint2*)(wih + i) = p;
  } else if (i < 1048576) {
    int k = i - 524288;
    const float* src = (k < 262144) ? whh_f : whh_b;
    f32x4 v = *(const f32x4*)(src + (k & 262143));
    int r = 0;
    r = __builtin_amdgcn_cvt_pk_fp8_f32(v[0], v[1], r, false);
    r = __builtin_amdgcn_cvt_pk_fp8_f32(v[2], v[3], r, true);
    *(unsigned int*)(whh8 + k) = (unsigned int)r;
  } else if (i < 1064960) {
    int k = i - 1048576;
    f32x4 v = *(const f32x4*)(wo + k);
    int r = 0;
    r = __builtin_amdgcn_cvt_pk_fp8_f32(v[0], v[1], r, false);
    r = __builtin_amdgcn_cvt_pk_fp8_f32(v[2], v[3], r, true);
    *(unsigned int*)(wout8 + k) = (unsigned int)r;
  }
}

// ---------------- persistent roles ----------------
// gx layout: [parity][dir][32 s][256 b][1024 g] bf16
//   parity stride 16,777,216 elems; dir 8,388,608; s 262,144.
// flags: ready[k*128 + ss*32 + dir*16 + sg] (target 1, single producer),
//        done[2048 + k] (target 32 = lstm blocks).

__device__ void gemm_role(
    const float* __restrict__ emb, const int* __restrict__ sent, const int* __restrict__ lens,
    const unsigned short* __restrict__ wih,
    const float* __restrict__ bih_f, const float* __restrict__ bhh_f,
    const float* __restrict__ bih_b, const float* __restrict__ bhh_b,
    unsigned short* __restrict__ gx, int* flags,
    unsigned short* xtile,      // [128][264] bf16 (row = st*16 + si)
    float* btile)               // [1024]
{
  int gb = blockIdx.x - 32;   // 0..223
  int tid = threadIdx.x, w = tid >> 6, lane = tid & 63, col = lane & 15, q = lane >> 4;
  int prev_chunk = -1;

  for (int idx = gb; idx < 2048; idx += 224) {
    int k = idx >> 7, t = idx & 127;
    int ss = t >> 5, dir = (t >> 4) & 1, sg = t & 15;
    if (k != prev_chunk) {
      prev_chunk = k;
      if (k >= 2) wait_ge(&flags[2048 + k - 2], 32);   // parity reuse backpressure
    }
    int b0 = sg * 16;
    int sbase = k * 32 + ss * 8;

    if (sbase < lens[b0]) {   // sorted desc: lens[b0] = group max
      // ---- stage x: 128 emb rows (16 sent x 8 steps) -> bf16 LDS, once ----
      {
        int r = tid >> 2, t4 = tid & 3;       // 4 threads per row, 64 f32 each
        int st = r >> 4, si = r & 15;
        int bidx = b0 + si;
        int len = lens[bidx];
        int s = sbase + st;
        int s_eff = dir ? ((s < len) ? (len - 1 - s) : s) : s;
        int token = sent[bidx * 512 + s_eff];
        const float* ep = emb + (size_t)token * 256 + t4 * 64;
        unsigned short* xd = xtile + r * 264 + t4 * 64;
#pragma unroll
        for (int u = 0; u < 4; u++) {
          f32x4 a0 = *(const f32x4*)(ep + u * 16);
          f32x4 a1 = *(const f32x4*)(ep + u * 16 + 4);
          f32x4 a2 = *(const f32x4*)(ep + u * 16 + 8);
          f32x4 a3 = *(const f32x4*)(ep + u * 16 + 12);
          uint4v p0, p1;
          p0[0] = f2bf(a0[0]) | ((unsigned int)f2bf(a0[1]) << 16);
          p0[1] = f2bf(a0[2]) | ((unsigned int)f2bf(a0[3]) << 16);
          p0[2] = f2bf(a1[0]) | ((unsigned int)f2bf(a1[1]) << 16);
          p0[3] = f2bf(a1[2]) | ((unsigned int)f2bf(a1[3]) << 16);
          p1[0] = f2bf(a2[0]) | ((unsigned int)f2bf(a2[1]) << 16);
          p1[1] = f2bf(a2[2]) | ((unsigned int)f2bf(a2[3]) << 16);
          p1[2] = f2bf(a3[0]) | ((unsigned int)f2bf(a3[1]) << 16);
          p1[3] = f2bf(a3[2]) | ((unsigned int)f2bf(a3[3]) << 16);
          *(uint4v*)(xd + u * 16) = p0;
          *(uint4v*)(xd + u * 16 + 8) = p1;
        }
        const float* bi = dir ? bih_b : bih_f;
        const float* bh = dir ? bhh_b : bhh_f;
        btile[tid] = bi[tid] + bh[tid];
        btile[tid + 512] = bi[tid + 512] + bh[tid + 512];
      }
      __syncthreads();

      // ---- compute: wave w -> gates [w*128, w*128+128), 2 blocks of 64 ----
      const unsigned short* wsrc = wih + (size_t)dir * 262144;
#pragma unroll
      for (int ntb = 0; ntb < 2; ntb++) {
        int gbase = w * 128 + ntb * 64;
        bf16x8 wf[8][4];
#pragma unroll
        for (int kt = 0; kt < 8; kt++)
#pragma unroll
          for (int nt = 0; nt < 4; nt++)
            wf[kt][nt] = *(const bf16x8*)(wsrc + (size_t)(gbase + nt * 16 + col) * 256 + kt * 32 + q * 8);
        f32x4 bias[4];
#pragma unroll
        for (int nt = 0; nt < 4; nt++)
#pragma unroll
          for (int rr = 0; rr < 4; rr++)
            bias[nt][rr] = btile[gbase + nt * 16 + q * 4 + rr];

#pragma unroll
        for (int st = 0; st < 8; st++) {
          bf16x8 xf[8];
#pragma unroll
          for (int kt = 0; kt < 8; kt++)
            xf[kt] = *(const bf16x8*)(xtile + (st * 16 + col) * 264 + kt * 32 + q * 8);
          f32x4 acc[4];
#pragma unroll
          for (int nt = 0; nt < 4; nt++) acc[nt] = bias[nt];
#pragma unroll
          for (int kt = 0; kt < 8; kt++)
#pragma unroll
            for (int nt = 0; nt < 4; nt++)
              acc[nt] = __builtin_amdgcn_mfma_f32_16x16x32_bf16(wf[kt][nt], xf[kt], acc[nt], 0, 0, 0);
          size_t off = (size_t)(k & 1) * 16777216 + (size_t)dir * 8388608
                     + (size_t)(ss * 8 + st) * 262144 + (size_t)(b0 + col) * 1024 + gbase;
#pragma unroll
          for (int nt = 0; nt < 4; nt++) {
            uint2 pk;
            pk.x = f2bf(acc[nt][0]) | ((unsigned int)f2bf(acc[nt][1]) << 16);
            pk.y = f2bf(acc[nt][2]) | ((unsigned int)f2bf(acc[nt][3]) << 16);
            *(uint2*)(gx + off + nt * 16 + q * 4) = pk;
          }
        }
      }
    }
    // tile done: barrier drains this block's gx stores, then device-scope release
    __syncthreads();
    if (tid == 0)
      __hip_atomic_fetch_add(&flags[k * 128 + ss * 32 + dir * 16 + sg], 1,
                             __ATOMIC_RELEASE, __HIP_MEMORY_SCOPE_AGENT);
  }
}

__device__ void lstm_role(
    const unsigned short* __restrict__ gx,
    const unsigned char* __restrict__ whh8,
    const unsigned char* __restrict__ wout8,
    const float* __restrict__ bout,
    const int* __restrict__ lens,
    unsigned short* __restrict__ emit_f, unsigned short* __restrict__ emit_b,
    int* flags, unsigned char (*hb4)[16 * 272])
{
  int bx = blockIdx.x;                 // 0..31
  int dir = bx & 1, grp = bx >> 1, b0 = grp * 16;   // grp = sg
  int tid = threadIdx.x, w = tid >> 6, lane = tid & 63, col = lane & 15, q = lane >> 4;
  int maxlen = lens[b0];               // sorted desc
  int bcl = b0 + col;                  // owned sentence (all 16 cols real)
  int mylen = lens[bcl];

  // ---- W_hh fp8 fragments for K=128 scaled MFMA: 8 row-tiles x 2 k-halves ----
  // With the 256-VGPR budget these stay register-resident for all 512 steps.
  const unsigned char* whb = whh8 + (size_t)dir * 262144;
  i32x8 wh[8][2];
#pragma unroll
  for (int t = 0; t < 8; t++) {
    int row0 = (t & 3) * 256 + w * 32 + (t >> 2) * 16;
#pragma unroll
    for (int kh = 0; kh < 2; kh++)
      wh[t][kh] = ld32(whb + (size_t)(row0 + col) * 256 + kh * 128 + q * 32);
  }

  // ---- emission weights fp8 K=128: every wave holds tag-half (w&1)*16 ----
  i32x8 wo[2];
  f32x4 bo4 = (f32x4){0.f, 0.f, 0.f, 0.f};
#pragma unroll
  for (int kh = 0; kh < 2; kh++)
    wo[kh] = ld32(wout8 + (size_t)((w & 1) * 16 + col) * 512 + dir * 256 + kh * 128 + q * 32);
  if (dir == 0) {
#pragma unroll
    for (int r = 0; r < 4; r++) bo4[r] = bout[(w & 1) * 16 + q * 4 + r];
  }
  unsigned short* ebase = dir ? emit_b : emit_f;

  // ---- persistent state (registers, whole sequence) ----
  float c8[8];
  i32x8 hf[2];
#pragma unroll
  for (int i = 0; i < 8; i++) c8[i] = 0.f;
#pragma unroll
  for (int kh = 0; kh < 2; kh++)
#pragma unroll
    for (int i = 0; i < 8; i++) hf[kh][i] = 0;

  for (int c = 0; c < 16; c++) {
    int s0 = c * 32;
    if (s0 < maxlen) {
      int cend = s0 + 32; if (cend > maxlen) cend = maxlen;
      const unsigned short* gbase = gx + (size_t)(c & 1) * 16777216 + (size_t)dir * 8388608
                                       + (size_t)bcl * 1024 + q * 4;
      for (int ss = 0; ss < 4; ss++) {
        int sp0 = s0 + ss * 8;
        if (sp0 >= maxlen) break;
        int spe = sp0 + 8; if (spe > cend) spe = cend;
        wait_ge(&flags[c * 128 + ss * 32 + dir * 16 + grp], 1);   // span produced

        uint2 gxr[8];
        {
          const unsigned short* gf = gbase + (size_t)(sp0 - s0) * 262144;
#pragma unroll
          for (int t = 0; t < 8; t++) {
            int row0 = (t & 3) * 256 + w * 32 + (t >> 2) * 16;
            gxr[t] = *(const uint2*)(gf + row0);
          }
        }

        for (int s = sp0; s < spe; s++) {
          f32x4 acc[8];
#pragma unroll
          for (int t = 0; t < 8; t++) {
            f32x4 a;
            a[0] = bf2f(gxr[t].x & 0xffffu); a[1] = bf2f(gxr[t].x >> 16);
            a[2] = bf2f(gxr[t].y & 0xffffu); a[3] = bf2f(gxr[t].y >> 16);
            acc[t] = a;
          }
          // prefetch gx for s+1 (within span only; span boundary reloads fresh)
          if (s + 1 < spe) {
            const unsigned short* gn = gbase + (size_t)(s + 1 - s0) * 262144;
#pragma unroll
            for (int t = 0; t < 8; t++) {
              int row0 = (t & 3) * 256 + w * 32 + (t >> 2) * 16;
              gxr[t] = *(const uint2*)(gn + row0);
            }
          }
          // h-part: MX-scaled fp8 MFMA K=128 (scales = 1.0), W resident
#pragma unroll
          for (int kh = 0; kh < 2; kh++) {
            i32x8 hv8 = hf[kh];
#pragma unroll
            for (int t = 0; t < 8; t++)
              acc[t] = __builtin_amdgcn_mfma_scale_f32_16x16x128_f8f6f4(
                  wh[t][kh], hv8, acc[t], 0, 0, 0, 127, 0, 127);
          }
          // gates
          float hv[8];
#pragma unroll
          for (int a = 0; a < 2; a++)
#pragma unroll
            for (int r = 0; r < 4; r++) {
              float ig = acc[a * 4 + 0][r], fg = acc[a * 4 + 1][r];
              float gg = acc[a * 4 + 2][r], og = acc[a * 4 + 3][r];
              float cn = fsig(fg) * c8[a * 4 + r] + fsig(ig) * ftanh(gg);
              c8[a * 4 + r] = cn;
              hv[a * 4 + r] = fsig(og) * ftanh(cn);
            }
          // write fp8 h to 8-deep LDS history
          int par = s & 7;
#pragma unroll
          for (int a = 0; a < 2; a++) {
            int r8 = 0;
            r8 = __builtin_amdgcn_cvt_pk_fp8_f32(hv[a * 4 + 0], hv[a * 4 + 1], r8, false);
            r8 = __builtin_amdgcn_cvt_pk_fp8_f32(hv[a * 4 + 2], hv[a * 4 + 3], r8, true);
            *(unsigned int*)(&hb4[par][col * 272 + w * 32 + a * 16 + q * 4]) = (unsigned int)r8;
          }
          lds_barrier();   // lgkmcnt(0)+s_barrier only: no vmcnt drain in the chain
#pragma unroll
          for (int kh = 0; kh < 2; kh++)
            hf[kh] = ld32(&hb4[par][col * 272 + kh * 128 + q * 32]);

          // batched emission: one wave-pair per buffered step, every 4 steps
          if ((s & 3) == 3 || s == spe - 1) {
            int ebeg = s & ~3;
            int e = ebeg + (w >> 1);
            if (e <= s) {
              f32x4 ea = bo4;
#pragma unroll
              for (int kh = 0; kh < 2; kh++) {
                i32x8 hbv = ld32(&hb4[e & 7][col * 272 + kh * 128 + q * 32]);
                ea = __builtin_amdgcn_mfma_scale_f32_16x16x128_f8f6f4(
                    wo[kh], hbv, ea, 0, 0, 0, 127, 0, 127);
              }
              if (e < mylen) {
                int pos = dir ? (mylen - 1 - e) : e;
                uint2 pk;
                pk.x = f2bf(ea[0]) | ((unsigned int)f2bf(ea[1]) << 16);
                pk.y = f2bf(ea[2]) | ((unsigned int)f2bf(ea[3]) << 16);
                *(uint2*)(ebase + (((size_t)bcl * 512 + pos) * 32 + (w & 1) * 16 + q * 4)) = pk;
              }
            }
          }
        }
      }
    }
    // consumed chunk c (or never needed it): release parity for chunk c+2
    __syncthreads();
    if (tid == 0)
      __hip_atomic_fetch_add(&flags[2048 + c], 1, __ATOMIC_RELEASE, __HIP_MEMORY_SCOPE_AGENT);
  }
}

__global__ __launch_bounds__(512)
__attribute__((amdgpu_waves_per_eu(2, 2)))
void fused_persist(
    const float* __restrict__ emb, const int* __restrict__ sent, const int* __restrict__ lens,
    const unsigned short* __restrict__ wih,
    const float* __restrict__ bih_f, const float* __restrict__ bhh_f,
    const float* __restrict__ bih_b, const float* __restrict__ bhh_b,
    unsigned short* __restrict__ gx,
    const unsigned char* __restrict__ whh8, const unsigned char* __restrict__ wout8,
    const float* __restrict__ bout,
    unsigned short* __restrict__ emit_f, unsigned short* __restrict__ emit_b,
    int* flags)
{
  __shared__ __align__(16) unsigned short xtile[128 * 264];
  __shared__ __align__(16) float btile[1024];
  __shared__ __align__(16) unsigned char hb4[8][16 * 272];

  if (blockIdx.x < 32) {
    lstm_role(gx, whh8, wout8, bout, lens, emit_f, emit_b, flags, hb4);
  } else {
    gemm_role(emb, sent, lens, wih, bih_f, bhh_f, bih_b, bhh_b, gx, flags, xtile, btile);
  }
}

// ---------------- K3: real-path score + CRF forward (bf16 emit in) ----------------
// 1 wave / sentence (256 blocks - latency-bound, keep max wave count).
__global__ __launch_bounds__(64) void crf_kernel(
    const unsigned short* __restrict__ emit_f,
    const unsigned short* __restrict__ emit_b,
    const float* __restrict__ trans, const int* __restrict__ tags,
    const int* __restrict__ lens, float* __restrict__ out) {
  const float LOG2E = 1.4426950408889634f, LN2 = 0.6931471805599453f;
  __shared__ __align__(16) float e_lds[512 * 32];   // 64 KB: log2e*(emit_f+emit_b)
  int b = blockIdx.x, lane = threadIdx.x;
  int len = lens[b];
  const int* tg = tags + b * 512;

  // ---- stage emit (coalesced bf16x8) -> LDS, pre-scaled by log2e ----
  size_t ebase = (size_t)b * 512 * 32;
  const unsigned short* pf = emit_f + ebase;
  const unsigned short* pb = emit_b + ebase;
  int ng = len * 4;                    // groups of 8 bf16
  for (int g = lane; g < ng; g += 64) {
    uint4v fv = *(const uint4v*)(pf + g * 8);
    uint4v bv = *(const uint4v*)(pb + g * 8);
    f32x4 w0, w1;
#pragma unroll
    for (int k = 0; k < 2; k++) {
      w0[2 * k]     = (bf2f(fv[k] & 0xffffu) + bf2f(bv[k] & 0xffffu)) * LOG2E;
      w0[2 * k + 1] = (bf2f(fv[k] >> 16)     + bf2f(bv[k] >> 16))     * LOG2E;
      w1[2 * k]     = (bf2f(fv[k + 2] & 0xffffu) + bf2f(bv[k + 2] & 0xffffu)) * LOG2E;
      w1[2 * k + 1] = (bf2f(fv[k + 2] >> 16)     + bf2f(bv[k + 2] >> 16))     * LOG2E;
    }
    *(f32x4*)(e_lds + g * 8) = w0;
    *(f32x4*)(e_lds + g * 8 + 4) = w1;
  }
  __syncthreads();

  // ---- real-path score (log2-scaled emit from LDS; trans in natural log) ----
  float rs2 = 0.f, rst = 0.f;
  for (int s = lane; s < len; s += 64) {
    int t1 = tg[s];
    rs2 += e_lds[s * 32 + t1];
    if (s > 0) rst += trans[tg[s - 1] * 32 + t1];
  }
  float rsc = LN2 * rs2 + rst;
#pragma unroll
  for (int m = 32; m; m >>= 1) rsc += __shfl_xor(rsc, m);

  // ---- CRF forward scan, log2 domain ----
  int j = lane & 31, half = lane >> 5, i0 = half * 16;
  float tr2[16];
  int pidx[16];
#pragma unroll
  for (int ii = 0; ii < 16; ii++) {
    tr2[ii] = trans[(i0 + ii) * 32 + j] * LOG2E;
    pidx[ii] = (i0 + ii) << 2;          // ds_bpermute byte index (hoisted)
  }
  const float* ep = e_lds + j;
  float B = ep[0];                       // log2-scaled alpha
  float e_nxt = ep[32];                  // len >= 256 always
  for (int s = 1; s < len; s++) {
    float e_cur = e_nxt;
    int sn = (s + 1 < len) ? (s + 1) : s;
    e_nxt = ep[sn * 32];                 // prefetch next step's emit (LDS)
    float v[16];
#pragma unroll
    for (int ii = 0; ii < 16; ii++)
      v[ii] = __builtin_bit_cast(float, __builtin_amdgcn_ds_bpermute(
                  pidx[ii], __builtin_bit_cast(int, B))) + tr2[ii];
    // depth-4 max tree
    float a8[8], a4[4], a2[2];
#pragma unroll
    for (int ii = 0; ii < 8; ii++) a8[ii] = fmaxf(v[ii], v[ii + 8]);
#pragma unroll
    for (int ii = 0; ii < 4; ii++) a4[ii] = fmaxf(a8[ii], a8[ii + 4]);
    a2[0] = fmaxf(a4[0], a4[2]); a2[1] = fmaxf(a4[1], a4[3]);
    float m1 = fmaxf(a2[0], a2[1]);
    float m2 = fmaxf(m1, __shfl_xor(m1, 32));
    // exp2 + depth-4 sum tree
    float x[16];
#pragma unroll
    for (int ii = 0; ii < 16; ii++) x[ii] = __builtin_amdgcn_exp2f(v[ii] - m2);
    float s8[8], s4[4], s2[2];
#pragma unroll
    for (int ii = 0; ii < 8; ii++) s8[ii] = x[ii] + x[ii + 8];
#pragma unroll
    for (int ii = 0; ii < 4; ii++) s4[ii] = s8[ii] + s8[ii + 4];
    s2[0] = s4[0] + s4[2]; s2[1] = s4[1] + s4[3];
    float sum = s2[0] + s2[1];
    sum += __shfl_xor(sum, 32);
    B = m2 + __builtin_amdgcn_logf(sum) + e_cur;   // v_log_f32 = log2
  }
  // log2-sum-exp2 over the 32 tags (halves hold identical B)
  float mz = B;
#pragma unroll
  for (int m = 16; m; m >>= 1) mz = fmaxf(mz, __shfl_xor(mz, m));
  float sz = __builtin_amdgcn_exp2f(B - mz);
#pragma unroll
  for (int m = 16; m; m >>= 1) sz += __shfl_xor(sz, m);
  float logz = LN2 * (mz + __builtin_amdgcn_logf(sz));
  if (lane == 0) out[b] = logz - rsc;
}

// ---------------- launch ----------------
extern "C" void kernel_launch(void* const* d_in, const int* in_sizes, int n_in,
                              void* d_out, int out_size, void* d_ws, size_t ws_size,
                              hipStream_t stream) {
  const float* emb   = (const float*)d_in[0];
  const float* Wih_f = (const float*)d_in[1];
  const float* Whh_f = (const float*)d_in[2];
  const float* bih_f = (const float*)d_in[3];
  const float* bhh_f = (const float*)d_in[4];
  const float* Wih_b = (const float*)d_in[5];
  const float* Whh_b = (const float*)d_in[6];
  const float* bih_b = (const float*)d_in[7];
  const float* bhh_b = (const float*)d_in[8];
  const float* Wout  = (const float*)d_in[9];
  const float* bout  = (const float*)d_in[10];
  const float* trans = (const float*)d_in[11];
  const int* sent = (const int*)d_in[12];
  const int* tags = (const int*)d_in[13];
  const int* lens = (const int*)d_in[14];
  float* out = (float*)d_out;

  // workspace layout (bytes), total 87,048,192
  char* ws = (char*)d_ws;
  if (ws_size < 87048192ull) return;
  unsigned short* gx      = (unsigned short*)(ws);                // 67,108,864 (2 parity x 32s)
  unsigned short* emit_f  = (unsigned short*)(ws + 67108864);     //  8,388,608
  unsigned short* emit_b  = (unsigned short*)(ws + 75497472);     //  8,388,608
  unsigned short* wih_bf  = (unsigned short*)(ws + 83886080);     //  1,048,576
  unsigned char*  whh8    = (unsigned char*)(ws + 84934656);      //    524,288
  unsigned char*  wout8   = (unsigned char*)(ws + 85458944);      //     16,384
  int*            flags   = (int*)(ws + 85475328);                //  8,320 (ready+done)

  cvt_weights<<<1040, 256, 0, stream>>>(Wih_f, Wih_b, Whh_f, Whh_b, Wout,
                                        wih_bf, whh8, wout8, flags);
  fused_persist<<<256, 512, 0, stream>>>(
      emb, sent, lens, wih_bf, bih_f, bhh_f, bih_b, bhh_b, gx,
      whh8, wout8, bout, emit_f, emit_b, flags);
  crf_kernel<<<256, 64, 0, stream>>>(emit_f, emit_b, trans, tags, lens, out);
}